// Round 1
// baseline (932.098 us; speedup 1.0000x reference)
//
#include <hip/hip_runtime.h>
#include <math.h>

#define T_BATCH 128
#define N_TOK   256
#define C_DIM   1408
#define CN1     16
#define KNN1    8
#define CN2     6
#define KNN2    3
#define NOUT    22   // CN2 + CN1

// ---------------------------------------------------------------------------
// Kernel A0: row squared norms. One wave per row (4 rows / 256-thread block).
// ---------------------------------------------------------------------------
__global__ __launch_bounds__(256) void rownorm_kernel(const float* __restrict__ x,
                                                      float* __restrict__ sq) {
    int row  = blockIdx.x * 4 + (threadIdx.x >> 6);
    int lane = threadIdx.x & 63;
    const float* xr = x + (size_t)row * C_DIM;
    float s = 0.f;
    for (int k = lane; k < C_DIM; k += 64) { float v = xr[k]; s += v * v; }
#pragma unroll
    for (int off = 32; off > 0; off >>= 1) s += __shfl_down(s, off);
    if (lane == 0) sq[row] = s;
}

// ---------------------------------------------------------------------------
// Kernel A: batched dist matrix. D[t,i,j] = sqrt(max(sq_i+sq_j-2*x_i.x_j,0))/sqrt(C)
// 64x64 tile per block, 4x4 per thread, K-chunks of 16, k-major LDS (stride 68).
// ---------------------------------------------------------------------------
__global__ __launch_bounds__(256) void gemm_dist_kernel(const float* __restrict__ x,
                                                        const float* __restrict__ sq,
                                                        float* __restrict__ dist) {
    const int t  = blockIdx.z;
    const int i0 = blockIdx.x * 64;
    const int j0 = blockIdx.y * 64;
    const float* X = x + (size_t)t * N_TOK * C_DIM;

    __shared__ float As[16][68];   // [k][row], stride 68 words (16B-aligned rows, <=2-way bank)
    __shared__ float Bs[16][68];

    const int tid = threadIdx.x;
    const int tx  = tid & 15;       // output col group
    const int ty  = tid >> 4;       // output row group
    const int lr  = tid >> 2;       // load row 0..63
    const int lc  = (tid & 3) * 4;  // load col group 0,4,8,12

    float acc[4][4] = {};

    for (int k0 = 0; k0 < C_DIM; k0 += 16) {
        float4 av = *(const float4*)&X[(size_t)(i0 + lr) * C_DIM + k0 + lc];
        float4 bv = *(const float4*)&X[(size_t)(j0 + lr) * C_DIM + k0 + lc];
        As[lc + 0][lr] = av.x; As[lc + 1][lr] = av.y; As[lc + 2][lr] = av.z; As[lc + 3][lr] = av.w;
        Bs[lc + 0][lr] = bv.x; Bs[lc + 1][lr] = bv.y; Bs[lc + 2][lr] = bv.z; Bs[lc + 3][lr] = bv.w;
        __syncthreads();
#pragma unroll
        for (int kk = 0; kk < 16; kk++) {
            float4 a = *(const float4*)&As[kk][ty * 4];
            float4 b = *(const float4*)&Bs[kk][tx * 4];
            float ar[4] = {a.x, a.y, a.z, a.w};
            float br[4] = {b.x, b.y, b.z, b.w};
#pragma unroll
            for (int r = 0; r < 4; r++)
#pragma unroll
                for (int c = 0; c < 4; c++) acc[r][c] += ar[r] * br[c];
        }
        __syncthreads();
    }

    const float inv_sqrtC = 1.0f / sqrtf((float)C_DIM);
    const float* sqt = sq + t * N_TOK;
    float* Dt = dist + (size_t)t * N_TOK * N_TOK;
#pragma unroll
    for (int r = 0; r < 4; r++) {
        int i = i0 + ty * 4 + r;
        float sqi = sqt[i];
        float4 o;
        float v[4];
#pragma unroll
        for (int c = 0; c < 4; c++) {
            int j = j0 + tx * 4 + c;
            float d2 = sqi + sqt[j] - 2.0f * acc[r][c];
            v[c] = sqrtf(fmaxf(d2, 0.0f)) * inv_sqrtC;
        }
        o.x = v[0]; o.y = v[1]; o.z = v[2]; o.w = v[3];
        *(float4*)&Dt[(size_t)i * N_TOK + j0 + tx * 4] = o;
    }
}

// ---------------------------------------------------------------------------
// Kernel B: layer-1 DPC. One block (256 threads) per batch; thread i owns row i.
// ---------------------------------------------------------------------------
__global__ __launch_bounds__(256) void dpc1_kernel(const float* __restrict__ dist,
                                                   int* __restrict__ idx1) {
    const int t = blockIdx.x;
    const int i = threadIdx.x;
    const float* D   = dist + (size_t)t * N_TOK * N_TOK;
    const float* row = D + (size_t)i * N_TOK;

    __shared__ float dens[N_TOK];
    __shared__ float scor[N_TOK];
    __shared__ float rmax[N_TOK];
    __shared__ int   centers[CN1];
    __shared__ float dmax_sh;

    // k=8 smallest distances (includes self ~0) + row max
    float m[KNN1];
#pragma unroll
    for (int q = 0; q < KNN1; q++) m[q] = 3.4e38f;
    float mx = 0.f;
    for (int j = 0; j < N_TOK; j++) {
        float d = row[j];
        mx = fmaxf(mx, d);
        if (d < m[KNN1 - 1]) {
            m[KNN1 - 1] = d;
#pragma unroll
            for (int q = KNN1 - 1; q > 0; q--) {
                if (m[q] < m[q - 1]) { float tmp = m[q]; m[q] = m[q - 1]; m[q - 1] = tmp; }
            }
        }
    }
    float s2 = 0.f;
#pragma unroll
    for (int q = 0; q < KNN1; q++) s2 += m[q] * m[q];
    float di = expf(-s2 / (float)KNN1);
    dens[i] = di;
    rmax[i] = mx;
    __syncthreads();

    if (i == 0) {
        float g = 0.f;
        for (int j = 0; j < N_TOK; j++) g = fmaxf(g, rmax[j]);
        dmax_sh = g;
    }
    __syncthreads();

    // parent distance: min dist to any strictly-denser token, else dist_max
    float pd = dmax_sh;
    for (int j = 0; j < N_TOK; j++) {
        float d = row[j];
        if (dens[j] > di) pd = fminf(pd, d);
    }
    scor[i] = pd * di;
    __syncthreads();

    // top-16 scores (descending, ties -> lowest index) — serial on thread 0
    if (i == 0) {
        for (int k = 0; k < CN1; k++) {
            float best = -3.4e38f; int bi = 0;
            for (int j = 0; j < N_TOK; j++) {
                if (scor[j] > best) { best = scor[j]; bi = j; }
            }
            centers[k] = bi;
            scor[bi] = -3.4e38f;
        }
    }
    __syncthreads();

    // assign to nearest center (first-min tie-break), override centers
    float bd = 3.4e38f; int bk = 0;
#pragma unroll
    for (int k = 0; k < CN1; k++) {
        float d = D[(size_t)centers[k] * N_TOK + i];
        if (d < bd) { bd = d; bk = k; }
    }
#pragma unroll
    for (int k = 0; k < CN1; k++) if (i == centers[k]) bk = k;
    idx1[t * N_TOK + i] = bk;
}

// ---------------------------------------------------------------------------
// Kernel C: merge1 (scatter-mean into 16 clusters). Grid (6 chunks, T batches).
// Thread = one channel; 16 static register accumulators (cndmask select).
// ---------------------------------------------------------------------------
__global__ __launch_bounds__(256) void merge1_kernel(const float* __restrict__ x,
                                                     const int* __restrict__ idx1,
                                                     float* __restrict__ meta1) {
    const int t   = blockIdx.y;
    const int ch  = blockIdx.x * 256 + threadIdx.x;
    const int tid = threadIdx.x;

    __shared__ int cidx[N_TOK];
    __shared__ int cnt[CN1];
    if (tid < CN1) cnt[tid] = 0;
    __syncthreads();
    int myc = idx1[t * N_TOK + tid];
    cidx[tid] = myc;
    atomicAdd(&cnt[myc], 1);
    __syncthreads();

    const bool act = (ch < C_DIM);
    const float* xb = x + (size_t)t * N_TOK * C_DIM;
    float acc[CN1];
#pragma unroll
    for (int q = 0; q < CN1; q++) acc[q] = 0.f;

    for (int j = 0; j < N_TOK; j++) {
        float v = act ? xb[(size_t)j * C_DIM + ch] : 0.f;
        int c = cidx[j];
#pragma unroll
        for (int q = 0; q < CN1; q++) acc[q] += (c == q) ? v : 0.f;
    }

    if (act) {
        float* mb = meta1 + (size_t)t * CN1 * C_DIM + ch;
#pragma unroll
        for (int q = 0; q < CN1; q++)
            mb[(size_t)q * C_DIM] = acc[q] / ((float)cnt[q] + 1e-6f);
    }
}

// ---------------------------------------------------------------------------
// Kernel DE: layer-2 DPC + merge2 + modulation + grouped output.
// One block (256 threads) per batch.
// ---------------------------------------------------------------------------
__global__ __launch_bounds__(256) void layer2_kernel(const float* __restrict__ meta1,
                                                     const float* __restrict__ score_w,
                                                     const float* __restrict__ score_b,
                                                     float* __restrict__ out) {
    const int t   = blockIdx.x;
    const int tid = threadIdx.x;
    const float* M = meta1 + (size_t)t * CN1 * C_DIM;

    __shared__ float buf[CN1][132];       // chunk of meta1 (pad 132 -> 2-way banks, 16B rows)
    __shared__ float d2s[CN1][CN1];
    __shared__ float m2[CN2][C_DIM];      // meta2: 6x1408 = 33.8 KB
    __shared__ float dens[CN1], scor[CN1], nrm[CN1], rmx[CN1];
    __shared__ int   centers[CN2], idx2s[CN1], cnt2[CN2];
    __shared__ float modu[CN2], msum[CN2];
    __shared__ int   srcRow[NOUT], cidArr[NOUT];
    __shared__ float dmax_sh;

    const int ti = tid >> 4;   // 0..15
    const int tj = tid & 15;   // 0..15

    // --- pairwise dots of meta1 rows (chunked through LDS) ---
    float acc = 0.f;
    for (int c0 = 0; c0 < C_DIM; c0 += 128) {
        for (int e = tid; e < CN1 * 128; e += 256) {
            int r = e >> 7, c = e & 127;
            buf[r][c] = M[(size_t)r * C_DIM + c0 + c];
        }
        __syncthreads();
#pragma unroll
        for (int cc = 0; cc < 128; cc += 4) {
            float4 a = *(const float4*)&buf[ti][cc];
            float4 b = *(const float4*)&buf[tj][cc];
            acc += a.x * b.x + a.y * b.y + a.z * b.z + a.w * b.w;
        }
        __syncthreads();
    }
    if (ti == tj) nrm[ti] = acc;
    __syncthreads();

    const float inv_sqrtC = 1.0f / sqrtf((float)C_DIM);
    {
        float d2 = nrm[ti] + nrm[tj] - 2.f * acc;
        d2s[ti][tj] = sqrtf(fmaxf(d2, 0.f)) * inv_sqrtC;
    }
    __syncthreads();

    // --- density (k=3), row max ---
    if (tid < CN1) {
        float m0 = 3.4e38f, m1 = 3.4e38f, m2v = 3.4e38f, mx = 0.f;
        for (int j = 0; j < CN1; j++) {
            float d = d2s[tid][j];
            mx = fmaxf(mx, d);
            if (d < m2v) {
                m2v = d;
                if (m2v < m1) { float tmp = m2v; m2v = m1; m1 = tmp; }
                if (m1 < m0)  { float tmp = m1;  m1 = m0;  m0 = tmp; }
            }
        }
        dens[tid] = expf(-(m0 * m0 + m1 * m1 + m2v * m2v) / (float)KNN2);
        rmx[tid] = mx;
    }
    __syncthreads();
    if (tid == 0) {
        float g = 0.f;
        for (int j = 0; j < CN1; j++) g = fmaxf(g, rmx[j]);
        dmax_sh = g;
    }
    __syncthreads();

    if (tid < CN1) {
        float di = dens[tid];
        float pd = dmax_sh;
        for (int j = 0; j < CN1; j++)
            if (dens[j] > di) pd = fminf(pd, d2s[tid][j]);
        scor[tid] = pd * di;
    }
    __syncthreads();

    if (tid == 0) {
        for (int k = 0; k < CN2; k++) {
            float best = -3.4e38f; int bi = 0;
            for (int j = 0; j < CN1; j++)
                if (scor[j] > best) { best = scor[j]; bi = j; }
            centers[k] = bi;
            scor[bi] = -3.4e38f;
        }
    }
    __syncthreads();

    if (tid < CN1) {
        float bd = 3.4e38f; int bk = 0;
#pragma unroll
        for (int k = 0; k < CN2; k++) {
            float d = d2s[centers[k]][tid];
            if (d < bd) { bd = d; bk = k; }
        }
#pragma unroll
        for (int k = 0; k < CN2; k++) if (tid == centers[k]) bk = k;
        idx2s[tid] = bk;
    }
    __syncthreads();

    if (tid == 0) {
        for (int v = 0; v < CN2; v++) cnt2[v] = 0;
        for (int i = 0; i < CN1; i++) cnt2[idx2s[i]]++;
        int slot = 0;
        for (int v = 0; v < CN2; v++) {
            srcRow[slot] = CN1 + v; cidArr[slot] = v; slot++;
            for (int i = 0; i < CN1; i++)
                if (idx2s[i] == v) { srcRow[slot] = i; cidArr[slot] = v; slot++; }
        }
        for (int v = 0; v < CN2; v++) msum[v] = 0.f;
    }
    __syncthreads();

    // --- meta2 (scatter-mean of meta1 into 6 clusters) + channel sums ---
    float ls[CN2] = {0.f, 0.f, 0.f, 0.f, 0.f, 0.f};
    for (int ch = tid; ch < C_DIM; ch += 256) {
        float a6[CN2] = {0.f, 0.f, 0.f, 0.f, 0.f, 0.f};
        for (int r = 0; r < CN1; r++) {
            float v = M[(size_t)r * C_DIM + ch];
            int c = idx2s[r];
#pragma unroll
            for (int q = 0; q < CN2; q++) a6[q] += (c == q) ? v : 0.f;
        }
#pragma unroll
        for (int q = 0; q < CN2; q++) {
            float mv = a6[q] / ((float)cnt2[q] + 1e-6f);
            m2[q][ch] = mv;
            ls[q] += mv;
        }
    }
#pragma unroll
    for (int q = 0; q < CN2; q++) atomicAdd(&msum[q], ls[q]);
    __syncthreads();

    // --- modulation: softmax(mean(meta2) @ W^T + b) ---
    if (tid == 0) {
        float mean[CN2], lg[CN2];
        for (int v = 0; v < CN2; v++) mean[v] = msum[v] / (float)C_DIM;
        float mxl = -3.4e38f;
        for (int u = 0; u < CN2; u++) {
            float s = score_b[u];
            for (int v = 0; v < CN2; v++) s += mean[v] * score_w[u * CN2 + v];
            lg[u] = s;
            mxl = fmaxf(mxl, s);
        }
        float den = 0.f;
        for (int u = 0; u < CN2; u++) { lg[u] = expf(lg[u] - mxl); den += lg[u]; }
        for (int u = 0; u < CN2; u++) modu[u] = lg[u] / den;
    }
    __syncthreads();

    // --- grouped, scaled output ---
    float* ob = out + (size_t)t * NOUT * C_DIM;
    for (int ch = tid; ch < C_DIM; ch += 256) {
#pragma unroll
        for (int s = 0; s < NOUT; s++) {
            int r = srcRow[s];
            float v = (r < CN1) ? M[(size_t)r * C_DIM + ch] : m2[r - CN1][ch];
            ob[(size_t)s * C_DIM + ch] = v * modu[cidArr[s]];
        }
    }
}

// ---------------------------------------------------------------------------
extern "C" void kernel_launch(void* const* d_in, const int* in_sizes, int n_in,
                              void* d_out, int out_size, void* d_ws, size_t ws_size,
                              hipStream_t stream) {
    const float* x  = (const float*)d_in[0];   // [128,256,1408]
    const float* sw = (const float*)d_in[1];   // [6,6]
    const float* sb = (const float*)d_in[2];   // [6]
    float* out = (float*)d_out;                // [128,22,1408]

    float* ws    = (float*)d_ws;
    float* sq    = ws;                                   // 32768
    float* dist  = sq + (size_t)T_BATCH * N_TOK;         // 8388608
    float* meta1 = dist + (size_t)T_BATCH * N_TOK * N_TOK; // 2883584
    int*   idx1  = (int*)(meta1 + (size_t)T_BATCH * CN1 * C_DIM); // 32768

    rownorm_kernel<<<(T_BATCH * N_TOK) / 4, 256, 0, stream>>>(x, sq);
    gemm_dist_kernel<<<dim3(N_TOK / 64, N_TOK / 64, T_BATCH), 256, 0, stream>>>(x, sq, dist);
    dpc1_kernel<<<T_BATCH, 256, 0, stream>>>(dist, idx1);
    merge1_kernel<<<dim3(6, T_BATCH), 256, 0, stream>>>(x, idx1, meta1);
    layer2_kernel<<<T_BATCH, 256, 0, stream>>>(meta1, sw, sb, out);
}

// Round 3
// 731.145 us; speedup vs baseline: 1.2748x; 1.2748x over previous
//
#include <hip/hip_runtime.h>
#include <math.h>

#define T_BATCH 128
#define N_TOK   256
#define C_DIM   1408
#define CN1     16
#define KNN1    8
#define CN2     6
#define KNN2    3
#define NOUT    22   // CN2 + CN1
#define LSTR    40   // LDS row stride in shorts (80 B): bank-group starts all distinct

typedef __attribute__((ext_vector_type(4))) short sh4;
typedef __attribute__((ext_vector_type(8))) short sh8;
typedef __attribute__((ext_vector_type(4))) float f32x4;

union frag_u { sh4 h[2]; sh8 v; };

__device__ inline sh8 ld_frag(const short* p) {
    frag_u u;
    u.h[0] = *(const sh4*)p;
    u.h[1] = *(const sh4*)(p + 4);
    return u.v;
}

struct bf16pair { short hi, lo; };

// split fp32 into bf16 hi + bf16 lo (both RNE)
__device__ inline bf16pair split_bf16(float v) {
    bf16pair r;
    unsigned u = __float_as_uint(v);
    unsigned h = (u + 0x7FFFu + ((u >> 16) & 1u)) >> 16;
    r.hi = (short)h;
    float l = v - __uint_as_float(h << 16);
    unsigned u2 = __float_as_uint(l);
    r.lo = (short)((u2 + 0x7FFFu + ((u2 >> 16) & 1u)) >> 16);
    return r;
}

// ---------------------------------------------------------------------------
// Kernel A0: row squared norms. One wave per row (4 rows / 256-thread block).
// ---------------------------------------------------------------------------
__global__ __launch_bounds__(256) void rownorm_kernel(const float* __restrict__ x,
                                                      float* __restrict__ sq) {
    int row  = blockIdx.x * 4 + (threadIdx.x >> 6);
    int lane = threadIdx.x & 63;
    const float* xr = x + (size_t)row * C_DIM;
    float s = 0.f;
    for (int k = lane; k < C_DIM; k += 64) { float v = xr[k]; s += v * v; }
#pragma unroll
    for (int off = 32; off > 0; off >>= 1) s += __shfl_down(s, off);
    if (lane == 0) sq[row] = s;
}

// ---------------------------------------------------------------------------
// Kernel A: dist via bf16x3 MFMA (hi*hi + hi*lo + lo*hi; lo*lo dropped).
// 64x64 tile/block, 4 waves, each wave = 32x32 via 2x2 of 16x16x32 MFMAs.
// ---------------------------------------------------------------------------
__global__ __launch_bounds__(256) void gemm_dist_mfma(const float* __restrict__ x,
                                                      const float* __restrict__ sq,
                                                      float* __restrict__ dist) {
    const int t  = blockIdx.z;
    const int i0 = blockIdx.x * 64;
    const int j0 = blockIdx.y * 64;
    const float* X = x + (size_t)t * N_TOK * C_DIM;

    __shared__ short Ahi[64 * LSTR], Alo[64 * LSTR], Bhi[64 * LSTR], Blo[64 * LSTR];

    const int tid  = threadIdx.x;
    const int wave = tid >> 6;
    const int lane = tid & 63;
    const int qr   = wave >> 1;       // wave row quadrant (0/1)
    const int qc   = wave & 1;        // wave col quadrant (0/1)
    const int srow = tid >> 2;        // staging row 0..63
    const int scol = (tid & 3) * 8;   // staging col group 0,8,16,24
    const int fr   = lane & 15;       // fragment row/col within 16
    const int fq   = lane >> 4;       // fragment quad -> k offset fq*8

    f32x4 acc[2][2];
#pragma unroll
    for (int a = 0; a < 2; a++)
#pragma unroll
        for (int b = 0; b < 2; b++) acc[a][b] = (f32x4){0.f, 0.f, 0.f, 0.f};

    const float* Arow = X + (size_t)(i0 + srow) * C_DIM + scol;
    const float* Brow = X + (size_t)(j0 + srow) * C_DIM + scol;

    for (int k0 = 0; k0 < C_DIM; k0 += 32) {
        // ---- stage 64x32 fp32 of A and B as bf16 hi/lo ----
        float4 a0 = *(const float4*)(Arow + k0);
        float4 a1 = *(const float4*)(Arow + k0 + 4);
        float4 b0 = *(const float4*)(Brow + k0);
        float4 b1 = *(const float4*)(Brow + k0 + 4);
        float av[8] = {a0.x, a0.y, a0.z, a0.w, a1.x, a1.y, a1.z, a1.w};
        float bv[8] = {b0.x, b0.y, b0.z, b0.w, b1.x, b1.y, b1.z, b1.w};
        sh4 ah0, ah1, al0, al1, bh0, bh1, bl0, bl1;
#pragma unroll
        for (int e = 0; e < 4; e++) {
            bf16pair pa0 = split_bf16(av[e]);     ah0[e] = pa0.hi; al0[e] = pa0.lo;
            bf16pair pa1 = split_bf16(av[e + 4]); ah1[e] = pa1.hi; al1[e] = pa1.lo;
            bf16pair pb0 = split_bf16(bv[e]);     bh0[e] = pb0.hi; bl0[e] = pb0.lo;
            bf16pair pb1 = split_bf16(bv[e + 4]); bh1[e] = pb1.hi; bl1[e] = pb1.lo;
        }
        __syncthreads();
        int so = srow * LSTR + scol;
        *(sh4*)&Ahi[so] = ah0;  *(sh4*)&Ahi[so + 4] = ah1;
        *(sh4*)&Alo[so] = al0;  *(sh4*)&Alo[so + 4] = al1;
        *(sh4*)&Bhi[so] = bh0;  *(sh4*)&Bhi[so + 4] = bh1;
        *(sh4*)&Blo[so] = bl0;  *(sh4*)&Blo[so + 4] = bl1;
        __syncthreads();

        // ---- fragments: A[m=fr][k=fq*8+j], two 16-row tiles per wave ----
        sh8 fAh[2], fAl[2], fBh[2], fBl[2];
#pragma unroll
        for (int mt = 0; mt < 2; mt++) {
            int ro = (qr * 32 + mt * 16 + fr) * LSTR + fq * 8;
            fAh[mt] = ld_frag(&Ahi[ro]);
            fAl[mt] = ld_frag(&Alo[ro]);
            int co = (qc * 32 + mt * 16 + fr) * LSTR + fq * 8;
            fBh[mt] = ld_frag(&Bhi[co]);
            fBl[mt] = ld_frag(&Blo[co]);
        }
#pragma unroll
        for (int mt = 0; mt < 2; mt++)
#pragma unroll
            for (int nt = 0; nt < 2; nt++) {
                acc[mt][nt] = __builtin_amdgcn_mfma_f32_16x16x32_bf16(fAh[mt], fBh[nt], acc[mt][nt], 0, 0, 0);
                acc[mt][nt] = __builtin_amdgcn_mfma_f32_16x16x32_bf16(fAh[mt], fBl[nt], acc[mt][nt], 0, 0, 0);
                acc[mt][nt] = __builtin_amdgcn_mfma_f32_16x16x32_bf16(fAl[mt], fBh[nt], acc[mt][nt], 0, 0, 0);
            }
    }

    // ---- epilogue: d = sqrt(max(sq_i+sq_j-2*dot,0))/sqrt(C); diag forced 0 ----
    const float inv_sqrtC = 1.0f / sqrtf((float)C_DIM);
    const float* sqt = sq + t * N_TOK;
    float* Dt = dist + (size_t)t * N_TOK * N_TOK;
#pragma unroll
    for (int mt = 0; mt < 2; mt++)
#pragma unroll
        for (int nt = 0; nt < 2; nt++) {
            int jg = j0 + qc * 32 + nt * 16 + fr;     // col = lane&15
            float sqj = sqt[jg];
#pragma unroll
            for (int r = 0; r < 4; r++) {
                int ig = i0 + qr * 32 + mt * 16 + fq * 4 + r;  // row = (lane>>4)*4+reg
                float d2 = sqt[ig] + sqj - 2.0f * acc[mt][nt][r];
                float v = (ig == jg) ? 0.0f : sqrtf(fmaxf(d2, 0.0f)) * inv_sqrtC;
                Dt[(size_t)ig * N_TOK + jg] = v;
            }
        }
}

// ---------------------------------------------------------------------------
// Kernel B1: density per row. One wave per row (4 rows / block).
// KNN k=8 via 8 rounds of wave-min extraction. Also rowmax -> atomicMax dmax.
// ---------------------------------------------------------------------------
__global__ __launch_bounds__(256) void density_kernel(const float* __restrict__ dist,
                                                      float* __restrict__ dens,
                                                      unsigned* __restrict__ dmax) {
    const int t    = blockIdx.y;
    const int i    = blockIdx.x * 4 + (threadIdx.x >> 6);
    const int lane = threadIdx.x & 63;
    const float* row = dist + (size_t)t * N_TOK * N_TOK + (size_t)i * N_TOK;

    float4 d4 = *(const float4*)(row + lane * 4);
    float v[4] = {d4.x, d4.y, d4.z, d4.w};

    float mx = fmaxf(fmaxf(v[0], v[1]), fmaxf(v[2], v[3]));
#pragma unroll
    for (int off = 32; off > 0; off >>= 1) mx = fmaxf(mx, __shfl_xor(mx, off));

    float s2 = 0.f;
#pragma unroll
    for (int it = 0; it < KNN1; it++) {
        float lm = fminf(fminf(v[0], v[1]), fminf(v[2], v[3]));
        float wm = lm;
#pragma unroll
        for (int off = 32; off > 0; off >>= 1) wm = fminf(wm, __shfl_xor(wm, off));
        bool has = (v[0] == wm) | (v[1] == wm) | (v[2] == wm) | (v[3] == wm);
        unsigned long long msk = __ballot(has);
        int owner = __ffsll((long long)msk) - 1;
        if (lane == owner) {
            if      (v[0] == wm) v[0] = 3.4e38f;
            else if (v[1] == wm) v[1] = 3.4e38f;
            else if (v[2] == wm) v[2] = 3.4e38f;
            else                 v[3] = 3.4e38f;
        }
        s2 += wm * wm;
    }
    if (lane == 0) {
        dens[t * N_TOK + i] = expf(-s2 / (float)KNN1);
        atomicMax(&dmax[t], __float_as_uint(mx));
    }
}

// ---------------------------------------------------------------------------
// Kernel B2: parent distance + score. One wave per row.
// ---------------------------------------------------------------------------
__global__ __launch_bounds__(256) void score_kernel(const float* __restrict__ dist,
                                                    const float* __restrict__ dens,
                                                    const unsigned* __restrict__ dmax,
                                                    float* __restrict__ score) {
    const int t    = blockIdx.y;
    const int i    = blockIdx.x * 4 + (threadIdx.x >> 6);
    const int lane = threadIdx.x & 63;
    const float* row = dist + (size_t)t * N_TOK * N_TOK + (size_t)i * N_TOK;

    float di = dens[t * N_TOK + i];
    float4 dd = *(const float4*)(row + lane * 4);
    float4 dj = *(const float4*)(dens + t * N_TOK + lane * 4);
    float pd = __uint_as_float(dmax[t]);
    if (dj.x > di) pd = fminf(pd, dd.x);
    if (dj.y > di) pd = fminf(pd, dd.y);
    if (dj.z > di) pd = fminf(pd, dd.z);
    if (dj.w > di) pd = fminf(pd, dd.w);
#pragma unroll
    for (int off = 32; off > 0; off >>= 1) pd = fminf(pd, __shfl_xor(pd, off));
    if (lane == 0) score[t * N_TOK + i] = pd * di;
}

// ---------------------------------------------------------------------------
// Kernel B3: top-16 scores (desc, ties->lowest idx) + nearest-center assign.
// One block (256 threads) per batch.
// ---------------------------------------------------------------------------
__global__ __launch_bounds__(256) void topk_assign_kernel(const float* __restrict__ dist,
                                                          const float* __restrict__ score,
                                                          int* __restrict__ idx1) {
    const int t   = blockIdx.x;
    const int tid = threadIdx.x;
    __shared__ unsigned long long wbest[4];
    __shared__ int centers[CN1];

    float s = score[t * N_TOK + tid];
    // scores >= 0 so float bits are order-monotone; low bits favor lower index
    unsigned long long key = ((unsigned long long)__float_as_uint(s) << 32)
                           | (unsigned)(65535 - tid);
    for (int k = 0; k < CN1; k++) {
        unsigned long long m = key;
#pragma unroll
        for (int off = 32; off > 0; off >>= 1) {
            unsigned long long o = __shfl_xor(m, off);
            m = (o > m) ? o : m;
        }
        if ((tid & 63) == 0) wbest[tid >> 6] = m;
        __syncthreads();
        unsigned long long b = wbest[0];
#pragma unroll
        for (int w = 1; w < 4; w++) b = (wbest[w] > b) ? wbest[w] : b;
        int idx = 65535 - (int)(b & 0xFFFFull);
        if (tid == 0) centers[k] = idx;
        if (tid == idx) key = 0;   // consumed
        __syncthreads();
    }

    const float* Dt = dist + (size_t)t * N_TOK * N_TOK;
    float bd = 3.4e38f; int bk = 0;
#pragma unroll
    for (int k = 0; k < CN1; k++) {
        float d = Dt[(size_t)centers[k] * N_TOK + tid];
        if (d < bd) { bd = d; bk = k; }
    }
#pragma unroll
    for (int k = 0; k < CN1; k++) if (tid == centers[k]) bk = k;
    idx1[t * N_TOK + tid] = bk;
}

// ---------------------------------------------------------------------------
// Kernel C: merge1 (scatter-mean into 16 clusters). Grid (6 chunks, T batches).
// ---------------------------------------------------------------------------
__global__ __launch_bounds__(256) void merge1_kernel(const float* __restrict__ x,
                                                     const int* __restrict__ idx1,
                                                     float* __restrict__ meta1) {
    const int t   = blockIdx.y;
    const int ch  = blockIdx.x * 256 + threadIdx.x;
    const int tid = threadIdx.x;

    __shared__ int cidx[N_TOK];
    __shared__ int cnt[CN1];
    if (tid < CN1) cnt[tid] = 0;
    __syncthreads();
    int myc = idx1[t * N_TOK + tid];
    cidx[tid] = myc;
    atomicAdd(&cnt[myc], 1);
    __syncthreads();

    const bool act = (ch < C_DIM);
    const float* xb = x + (size_t)t * N_TOK * C_DIM;
    float acc[CN1];
#pragma unroll
    for (int q = 0; q < CN1; q++) acc[q] = 0.f;

    for (int j = 0; j < N_TOK; j++) {
        float v = act ? xb[(size_t)j * C_DIM + ch] : 0.f;
        int c = cidx[j];
#pragma unroll
        for (int q = 0; q < CN1; q++) acc[q] += (c == q) ? v : 0.f;
    }

    if (act) {
        float* mb = meta1 + (size_t)t * CN1 * C_DIM + ch;
#pragma unroll
        for (int q = 0; q < CN1; q++)
            mb[(size_t)q * C_DIM] = acc[q] / ((float)cnt[q] + 1e-6f);
    }
}

// ---------------------------------------------------------------------------
// Kernel DE: layer-2 DPC + merge2 + modulation + grouped output.
// One block (256 threads) per batch.
// ---------------------------------------------------------------------------
__global__ __launch_bounds__(256) void layer2_kernel(const float* __restrict__ meta1,
                                                     const float* __restrict__ score_w,
                                                     const float* __restrict__ score_b,
                                                     float* __restrict__ out) {
    const int t   = blockIdx.x;
    const int tid = threadIdx.x;
    const float* M = meta1 + (size_t)t * CN1 * C_DIM;

    __shared__ float buf[CN1][132];
    __shared__ float d2s[CN1][CN1];
    __shared__ float m2[CN2][C_DIM];
    __shared__ float dens[CN1], scor[CN1], nrm[CN1], rmx[CN1];
    __shared__ int   centers[CN2], idx2s[CN1], cnt2[CN2];
    __shared__ float modu[CN2], msum[CN2];
    __shared__ int   srcRow[NOUT], cidArr[NOUT];
    __shared__ float dmax_sh;

    const int ti = tid >> 4;
    const int tj = tid & 15;

    float acc = 0.f;
    for (int c0 = 0; c0 < C_DIM; c0 += 128) {
        for (int e = tid; e < CN1 * 128; e += 256) {
            int r = e >> 7, c = e & 127;
            buf[r][c] = M[(size_t)r * C_DIM + c0 + c];
        }
        __syncthreads();
#pragma unroll
        for (int cc = 0; cc < 128; cc += 4) {
            float4 a = *(const float4*)&buf[ti][cc];
            float4 b = *(const float4*)&buf[tj][cc];
            acc += a.x * b.x + a.y * b.y + a.z * b.z + a.w * b.w;
        }
        __syncthreads();
    }
    if (ti == tj) nrm[ti] = acc;
    __syncthreads();

    const float inv_sqrtC = 1.0f / sqrtf((float)C_DIM);
    {
        float d2 = nrm[ti] + nrm[tj] - 2.f * acc;
        d2s[ti][tj] = sqrtf(fmaxf(d2, 0.f)) * inv_sqrtC;
    }
    __syncthreads();

    if (tid < CN1) {
        float m0 = 3.4e38f, m1 = 3.4e38f, m2v = 3.4e38f, mx = 0.f;
        for (int j = 0; j < CN1; j++) {
            float d = d2s[tid][j];
            mx = fmaxf(mx, d);
            if (d < m2v) {
                m2v = d;
                if (m2v < m1) { float tmp = m2v; m2v = m1; m1 = tmp; }
                if (m1 < m0)  { float tmp = m1;  m1 = m0;  m0 = tmp; }
            }
        }
        dens[tid] = expf(-(m0 * m0 + m1 * m1 + m2v * m2v) / (float)KNN2);
        rmx[tid] = mx;
    }
    __syncthreads();
    if (tid == 0) {
        float g = 0.f;
        for (int j = 0; j < CN1; j++) g = fmaxf(g, rmx[j]);
        dmax_sh = g;
    }
    __syncthreads();

    if (tid < CN1) {
        float di = dens[tid];
        float pd = dmax_sh;
        for (int j = 0; j < CN1; j++)
            if (dens[j] > di) pd = fminf(pd, d2s[tid][j]);
        scor[tid] = pd * di;
    }
    __syncthreads();

    if (tid == 0) {
        for (int k = 0; k < CN2; k++) {
            float best = -3.4e38f; int bi = 0;
            for (int j = 0; j < CN1; j++)
                if (scor[j] > best) { best = scor[j]; bi = j; }
            centers[k] = bi;
            scor[bi] = -3.4e38f;
        }
    }
    __syncthreads();

    if (tid < CN1) {
        float bd = 3.4e38f; int bk = 0;
#pragma unroll
        for (int k = 0; k < CN2; k++) {
            float d = d2s[centers[k]][tid];
            if (d < bd) { bd = d; bk = k; }
        }
#pragma unroll
        for (int k = 0; k < CN2; k++) if (tid == centers[k]) bk = k;
        idx2s[tid] = bk;
    }
    __syncthreads();

    if (tid == 0) {
        for (int v = 0; v < CN2; v++) cnt2[v] = 0;
        for (int i = 0; i < CN1; i++) cnt2[idx2s[i]]++;
        int slot = 0;
        for (int v = 0; v < CN2; v++) {
            srcRow[slot] = CN1 + v; cidArr[slot] = v; slot++;
            for (int i = 0; i < CN1; i++)
                if (idx2s[i] == v) { srcRow[slot] = i; cidArr[slot] = v; slot++; }
        }
        for (int v = 0; v < CN2; v++) msum[v] = 0.f;
    }
    __syncthreads();

    float ls[CN2] = {0.f, 0.f, 0.f, 0.f, 0.f, 0.f};
    for (int ch = tid; ch < C_DIM; ch += 256) {
        float a6[CN2] = {0.f, 0.f, 0.f, 0.f, 0.f, 0.f};
        for (int r = 0; r < CN1; r++) {
            float v = M[(size_t)r * C_DIM + ch];
            int c = idx2s[r];
#pragma unroll
            for (int q = 0; q < CN2; q++) a6[q] += (c == q) ? v : 0.f;
        }
#pragma unroll
        for (int q = 0; q < CN2; q++) {
            float mv = a6[q] / ((float)cnt2[q] + 1e-6f);
            m2[q][ch] = mv;
            ls[q] += mv;
        }
    }
#pragma unroll
    for (int q = 0; q < CN2; q++) atomicAdd(&msum[q], ls[q]);
    __syncthreads();

    if (tid == 0) {
        float mean[CN2], lg[CN2];
        for (int v = 0; v < CN2; v++) mean[v] = msum[v] / (float)C_DIM;
        float mxl = -3.4e38f;
        for (int u = 0; u < CN2; u++) {
            float s = score_b[u];
            for (int v = 0; v < CN2; v++) s += mean[v] * score_w[u * CN2 + v];
            lg[u] = s;
            mxl = fmaxf(mxl, s);
        }
        float den = 0.f;
        for (int u = 0; u < CN2; u++) { lg[u] = expf(lg[u] - mxl); den += lg[u]; }
        for (int u = 0; u < CN2; u++) modu[u] = lg[u] / den;
    }
    __syncthreads();

    float* ob = out + (size_t)t * NOUT * C_DIM;
    for (int ch = tid; ch < C_DIM; ch += 256) {
#pragma unroll
        for (int s = 0; s < NOUT; s++) {
            int r = srcRow[s];
            float v = (r < CN1) ? M[(size_t)r * C_DIM + ch] : m2[r - CN1][ch];
            ob[(size_t)s * C_DIM + ch] = v * modu[cidArr[s]];
        }
    }
}

// ---------------------------------------------------------------------------
extern "C" void kernel_launch(void* const* d_in, const int* in_sizes, int n_in,
                              void* d_out, int out_size, void* d_ws, size_t ws_size,
                              hipStream_t stream) {
    const float* x  = (const float*)d_in[0];   // [128,256,1408]
    const float* sw = (const float*)d_in[1];   // [6,6]
    const float* sb = (const float*)d_in[2];   // [6]
    float* out = (float*)d_out;                // [128,22,1408]

    float* ws     = (float*)d_ws;
    float* sq     = ws;                                        // 32768 f
    float* dist   = sq + (size_t)T_BATCH * N_TOK;              // 8388608 f
    float* meta1  = dist + (size_t)T_BATCH * N_TOK * N_TOK;    // 2883584 f
    int*   idx1   = (int*)(meta1 + (size_t)T_BATCH * CN1 * C_DIM); // 32768 i
    float* dens   = (float*)(idx1 + (size_t)T_BATCH * N_TOK);  // 32768 f
    float* score  = dens + (size_t)T_BATCH * N_TOK;            // 32768 f
    unsigned* dmax = (unsigned*)(score + (size_t)T_BATCH * N_TOK); // 128 u

    (void)hipMemsetAsync(dmax, 0, T_BATCH * sizeof(unsigned), stream);
    rownorm_kernel<<<(T_BATCH * N_TOK) / 4, 256, 0, stream>>>(x, sq);
    gemm_dist_mfma<<<dim3(N_TOK / 64, N_TOK / 64, T_BATCH), 256, 0, stream>>>(x, sq, dist);
    density_kernel<<<dim3(N_TOK / 4, T_BATCH), 256, 0, stream>>>(dist, dens, dmax);
    score_kernel<<<dim3(N_TOK / 4, T_BATCH), 256, 0, stream>>>(dist, dens, dmax, score);
    topk_assign_kernel<<<T_BATCH, 256, 0, stream>>>(dist, score, idx1);
    merge1_kernel<<<dim3(6, T_BATCH), 256, 0, stream>>>(x, idx1, meta1);
    layer2_kernel<<<T_BATCH, 256, 0, stream>>>(meta1, sw, sb, out);
}

// Round 4
// 503.939 us; speedup vs baseline: 1.8496x; 1.4509x over previous
//
#include <hip/hip_runtime.h>
#include <math.h>

#define T_BATCH 128
#define N_TOK   256
#define C_DIM   1408
#define CN1     16
#define KNN1    8
#define CN2     6
#define KNN2    3
#define NOUT    22   // CN2 + CN1
#define LSTR    40   // LDS row stride in shorts (80 B): 2-way bank groups (free)

typedef __attribute__((ext_vector_type(4))) short sh4;
typedef __attribute__((ext_vector_type(8))) short sh8;
typedef __attribute__((ext_vector_type(4))) float f32x4;

union frag_u { sh4 h[2]; sh8 v; };

__device__ inline sh8 ld_frag(const short* p) {
    frag_u u;
    u.h[0] = *(const sh4*)p;
    u.h[1] = *(const sh4*)(p + 4);
    return u.v;
}

struct bf16pair { short hi, lo; };

// split fp32 into bf16 hi + bf16 lo (both RNE)
__device__ inline bf16pair split_bf16(float v) {
    bf16pair r;
    unsigned u = __float_as_uint(v);
    unsigned h = (u + 0x7FFFu + ((u >> 16) & 1u)) >> 16;
    r.hi = (short)h;
    float l = v - __uint_as_float(h << 16);
    unsigned u2 = __float_as_uint(l);
    r.lo = (short)((u2 + 0x7FFFu + ((u2 >> 16) & 1u)) >> 16);
    return r;
}

// ---------------------------------------------------------------------------
// Kernel A: dist via bf16x3 MFMA, 128x128 tile/block, 4 waves (each 64x64 =
// 4x4 of 16x16x32). Row norms computed from the same staged data (fused
// rownorm). D[t,i,j] = sqrt(max(sq_i+sq_j-2*dot,0))/sqrt(C), diag forced 0.
// ---------------------------------------------------------------------------
__global__ __launch_bounds__(256, 2) void gemm_dist_mfma(const float* __restrict__ x,
                                                         float* __restrict__ dist) {
    const int t  = blockIdx.z;
    const int i0 = blockIdx.x * 128;
    const int j0 = blockIdx.y * 128;
    const float* X = x + (size_t)t * N_TOK * C_DIM;

    __shared__ short Ahi[128 * LSTR], Alo[128 * LSTR], Bhi[128 * LSTR], Blo[128 * LSTR];
    __shared__ float nred[512];
    __shared__ float snA[128], snB[128];

    const int tid  = threadIdx.x;
    const int wave = tid >> 6;
    const int lane = tid & 63;
    const int qr   = wave >> 1;        // wave row half (0/1)
    const int qc   = wave & 1;         // wave col half (0/1)
    const int srow = tid >> 1;         // staging row 0..127
    const int scol = (tid & 1) * 16;   // staging col group 0 or 16
    const int fr   = lane & 15;
    const int fq   = lane >> 4;        // k offset fq*8

    f32x4 acc[4][4];
#pragma unroll
    for (int a = 0; a < 4; a++)
#pragma unroll
        for (int b = 0; b < 4; b++) acc[a][b] = (f32x4){0.f, 0.f, 0.f, 0.f};

    const float* Arow = X + (size_t)(i0 + srow) * C_DIM + scol;
    const float* Brow = X + (size_t)(j0 + srow) * C_DIM + scol;
    float nA = 0.f, nB = 0.f;

    for (int k0 = 0; k0 < C_DIM; k0 += 32) {
        float av[16], bv[16];
#pragma unroll
        for (int g = 0; g < 4; g++) {
            float4 a = *(const float4*)(Arow + k0 + g * 4);
            float4 b = *(const float4*)(Brow + k0 + g * 4);
            av[g * 4 + 0] = a.x; av[g * 4 + 1] = a.y; av[g * 4 + 2] = a.z; av[g * 4 + 3] = a.w;
            bv[g * 4 + 0] = b.x; bv[g * 4 + 1] = b.y; bv[g * 4 + 2] = b.z; bv[g * 4 + 3] = b.w;
        }
#pragma unroll
        for (int e = 0; e < 16; e++) { nA += av[e] * av[e]; nB += bv[e] * bv[e]; }

        sh4 AH[4], AL[4], BH[4], BL[4];
#pragma unroll
        for (int g = 0; g < 4; g++)
#pragma unroll
            for (int e = 0; e < 4; e++) {
                bf16pair pa = split_bf16(av[g * 4 + e]); AH[g][e] = pa.hi; AL[g][e] = pa.lo;
                bf16pair pb = split_bf16(bv[g * 4 + e]); BH[g][e] = pb.hi; BL[g][e] = pb.lo;
            }
        __syncthreads();
        int so = srow * LSTR + scol;
#pragma unroll
        for (int g = 0; g < 4; g++) {
            *(sh4*)&Ahi[so + g * 4] = AH[g];
            *(sh4*)&Alo[so + g * 4] = AL[g];
            *(sh4*)&Bhi[so + g * 4] = BH[g];
            *(sh4*)&Blo[so + g * 4] = BL[g];
        }
        __syncthreads();

        sh8 fAh[4], fAl[4], fBh[4], fBl[4];
#pragma unroll
        for (int mt = 0; mt < 4; mt++) {
            int ro = (qr * 64 + mt * 16 + fr) * LSTR + fq * 8;
            fAh[mt] = ld_frag(&Ahi[ro]);
            fAl[mt] = ld_frag(&Alo[ro]);
            int co = (qc * 64 + mt * 16 + fr) * LSTR + fq * 8;
            fBh[mt] = ld_frag(&Bhi[co]);
            fBl[mt] = ld_frag(&Blo[co]);
        }
#pragma unroll
        for (int mt = 0; mt < 4; mt++)
#pragma unroll
            for (int nt = 0; nt < 4; nt++) {
                acc[mt][nt] = __builtin_amdgcn_mfma_f32_16x16x32_bf16(fAh[mt], fBh[nt], acc[mt][nt], 0, 0, 0);
                acc[mt][nt] = __builtin_amdgcn_mfma_f32_16x16x32_bf16(fAh[mt], fBl[nt], acc[mt][nt], 0, 0, 0);
                acc[mt][nt] = __builtin_amdgcn_mfma_f32_16x16x32_bf16(fAl[mt], fBh[nt], acc[mt][nt], 0, 0, 0);
            }
    }

    // fused row norms: snA[r] = sum over cols (cols 0-15 part + cols 16-31 part)
    nred[tid] = nA; nred[256 + tid] = nB;
    __syncthreads();
    if (tid < 128) {
        snA[tid] = nred[2 * tid] + nred[2 * tid + 1];
        snB[tid] = nred[256 + 2 * tid] + nred[256 + 2 * tid + 1];
    }
    __syncthreads();

    const float inv_sqrtC = 1.0f / sqrtf((float)C_DIM);
    float* Dt = dist + (size_t)t * N_TOK * N_TOK;
#pragma unroll
    for (int mt = 0; mt < 4; mt++)
#pragma unroll
        for (int nt = 0; nt < 4; nt++) {
            int jl = qc * 64 + nt * 16 + fr;
            float sqj = snB[jl];
            int jg = j0 + jl;
#pragma unroll
            for (int r = 0; r < 4; r++) {
                int il = qr * 64 + mt * 16 + fq * 4 + r;
                int ig = i0 + il;
                float d2 = snA[il] + sqj - 2.0f * acc[mt][nt][r];
                float v = (ig == jg) ? 0.0f : sqrtf(fmaxf(d2, 0.0f)) * inv_sqrtC;
                Dt[(size_t)ig * N_TOK + jg] = v;
            }
        }
}

// ---------------------------------------------------------------------------
// Kernel B1: density. Thread per column i (symmetry: col i == row i to 1 ulp).
// Branchless 8-reg insertion sort, no cross-lane ops in the scan.
// ---------------------------------------------------------------------------
__global__ __launch_bounds__(64) void density_kernel(const float* __restrict__ dist,
                                                     float* __restrict__ dens,
                                                     unsigned* __restrict__ dmax) {
    const int t    = blockIdx.y;
    const int lane = threadIdx.x;
    const int i    = blockIdx.x * 64 + lane;
    const float* D = dist + (size_t)t * N_TOK * N_TOK;

    float m[KNN1];
#pragma unroll
    for (int q = 0; q < KNN1; q++) m[q] = 3.4e38f;
    float mx = 0.f;

#pragma unroll 8
    for (int j = 0; j < N_TOK; j++) {
        float d = D[(size_t)j * N_TOK + i];
        mx = fmaxf(mx, d);
        float xv = d;
#pragma unroll
        for (int q = 0; q < KNN1; q++) {
            float lo = fminf(m[q], xv);
            xv = fmaxf(m[q], xv);
            m[q] = lo;
        }
    }
    float s2 = 0.f;
#pragma unroll
    for (int q = 0; q < KNN1; q++) s2 += m[q] * m[q];
    dens[t * N_TOK + i] = expf(-s2 / (float)KNN1);

#pragma unroll
    for (int off = 32; off > 0; off >>= 1) mx = fmaxf(mx, __shfl_xor(mx, off));
    if (lane == 0) atomicMax(&dmax[t], __float_as_uint(mx));
}

// ---------------------------------------------------------------------------
// Kernel B2: parent distance + score. Thread per column i (symmetry).
// ---------------------------------------------------------------------------
__global__ __launch_bounds__(64) void score_kernel(const float* __restrict__ dist,
                                                   const float* __restrict__ dens,
                                                   const unsigned* __restrict__ dmax,
                                                   float* __restrict__ score) {
    const int t    = blockIdx.y;
    const int lane = threadIdx.x;
    const int i    = blockIdx.x * 64 + lane;
    const float* D = dist + (size_t)t * N_TOK * N_TOK;

    __shared__ float sd[N_TOK];
#pragma unroll
    for (int u = 0; u < 4; u++) sd[u * 64 + lane] = dens[t * N_TOK + u * 64 + lane];
    __syncthreads();

    float di = sd[i & (N_TOK - 1)];
    di = dens[t * N_TOK + i];   // exact own value
    float pd = __uint_as_float(dmax[t]);
#pragma unroll 8
    for (int j = 0; j < N_TOK; j++) {
        float d = D[(size_t)j * N_TOK + i];
        float dj = sd[j];
        pd = (dj > di) ? fminf(pd, d) : pd;
    }
    score[t * N_TOK + i] = pd * di;
}

// ---------------------------------------------------------------------------
// Kernel B3: top-16 scores (desc, ties->lowest idx) + nearest-center assign +
// per-cluster member lists (deterministic, ascending token order).
// One block (256 threads) per batch.
// ---------------------------------------------------------------------------
__global__ __launch_bounds__(256) void topk_assign_kernel(const float* __restrict__ dist,
                                                          const float* __restrict__ score,
                                                          int* __restrict__ memb,
                                                          int* __restrict__ cntg,
                                                          int* __restrict__ offg) {
    const int t   = blockIdx.x;
    const int tid = threadIdx.x;
    __shared__ unsigned long long wbest[4];
    __shared__ int centers[CN1];
    __shared__ int bks[N_TOK];
    __shared__ int cnt_s[CN1], off_s[CN1];

    float s = score[t * N_TOK + tid];
    unsigned long long key = ((unsigned long long)__float_as_uint(s) << 32)
                           | (unsigned)(65535 - tid);
    for (int k = 0; k < CN1; k++) {
        unsigned long long m = key;
#pragma unroll
        for (int off = 32; off > 0; off >>= 1) {
            unsigned long long o = __shfl_xor(m, off);
            m = (o > m) ? o : m;
        }
        if ((tid & 63) == 0) wbest[tid >> 6] = m;
        __syncthreads();
        unsigned long long b = wbest[0];
#pragma unroll
        for (int w = 1; w < 4; w++) b = (wbest[w] > b) ? wbest[w] : b;
        int idx = 65535 - (int)(b & 0xFFFFull);
        if (tid == 0) centers[k] = idx;
        if (tid == idx) key = 0;
        __syncthreads();
    }

    const float* Dt = dist + (size_t)t * N_TOK * N_TOK;
    float bd = 3.4e38f; int bk = 0;
#pragma unroll
    for (int k = 0; k < CN1; k++) {
        float d = Dt[(size_t)centers[k] * N_TOK + tid];
        if (d < bd) { bd = d; bk = k; }
    }
#pragma unroll
    for (int k = 0; k < CN1; k++) if (tid == centers[k]) bk = k;

    bks[tid] = bk;
    __syncthreads();
    if (tid < CN1) {
        int c = 0;
        for (int j = 0; j < N_TOK; j++) c += (bks[j] == tid);
        cnt_s[tid] = c;
    }
    __syncthreads();
    if (tid == 0) {
        int o = 0;
        for (int q = 0; q < CN1; q++) { off_s[q] = o; o += cnt_s[q]; }
    }
    __syncthreads();
    int rank = 0;
    for (int j = 0; j < tid; j++) rank += (bks[j] == bk);
    memb[t * N_TOK + off_s[bk] + rank] = tid;
    if (tid < CN1) {
        cntg[t * CN1 + tid] = cnt_s[tid];
        offg[t * CN1 + tid] = off_s[tid];
    }
}

// ---------------------------------------------------------------------------
// Kernel C: merge1 via member lists. Block (cluster q, batch t) sums its
// members' rows; 1 add per element instead of 16 selects.
// ---------------------------------------------------------------------------
__global__ __launch_bounds__(256) void merge1_kernel(const float* __restrict__ x,
                                                     const int* __restrict__ memb,
                                                     const int* __restrict__ cntg,
                                                     const int* __restrict__ offg,
                                                     float* __restrict__ meta1) {
    const int q   = blockIdx.x;
    const int t   = blockIdx.y;
    const int tid = threadIdx.x;
    const int n    = cntg[t * CN1 + q];
    const int base = t * N_TOK + offg[t * CN1 + q];
    const int c0 = tid, c1 = tid + 256;        // float4 indices; 352 per row
    const bool act1 = (c1 < C_DIM / 4);

    float a0x = 0.f, a0y = 0.f, a0z = 0.f, a0w = 0.f;
    float a1x = 0.f, a1y = 0.f, a1z = 0.f, a1w = 0.f;
    for (int m = 0; m < n; m++) {
        int row = memb[base + m];
        const float4* xr = (const float4*)(x + ((size_t)t * N_TOK + row) * C_DIM);
        float4 v0 = xr[c0];
        a0x += v0.x; a0y += v0.y; a0z += v0.z; a0w += v0.w;
        if (act1) {
            float4 v1 = xr[c1];
            a1x += v1.x; a1y += v1.y; a1z += v1.z; a1w += v1.w;
        }
    }
    float w = 1.0f / ((float)n + 1e-6f);
    float4* mr = (float4*)(meta1 + ((size_t)t * CN1 + q) * C_DIM);
    float4 o0; o0.x = a0x * w; o0.y = a0y * w; o0.z = a0z * w; o0.w = a0w * w;
    mr[c0] = o0;
    if (act1) {
        float4 o1; o1.x = a1x * w; o1.y = a1y * w; o1.z = a1z * w; o1.w = a1w * w;
        mr[c1] = o1;
    }
}

// ---------------------------------------------------------------------------
// Kernel DE: layer-2 DPC + merge2 + modulation + grouped output.
// One block (256 threads) per batch.
// ---------------------------------------------------------------------------
__global__ __launch_bounds__(256) void layer2_kernel(const float* __restrict__ meta1,
                                                     const float* __restrict__ score_w,
                                                     const float* __restrict__ score_b,
                                                     float* __restrict__ out) {
    const int t   = blockIdx.x;
    const int tid = threadIdx.x;
    const float* M = meta1 + (size_t)t * CN1 * C_DIM;

    __shared__ float buf[CN1][132];
    __shared__ float d2s[CN1][CN1];
    __shared__ float m2[CN2][C_DIM];
    __shared__ float dens[CN1], scor[CN1], nrm[CN1], rmx[CN1];
    __shared__ int   centers[CN2], idx2s[CN1], cnt2[CN2];
    __shared__ float modu[CN2], msum[CN2];
    __shared__ int   srcRow[NOUT], cidArr[NOUT];
    __shared__ float dmax_sh;

    const int ti = tid >> 4;
    const int tj = tid & 15;

    float acc = 0.f;
    for (int c0 = 0; c0 < C_DIM; c0 += 128) {
        for (int e = tid; e < CN1 * 128; e += 256) {
            int r = e >> 7, c = e & 127;
            buf[r][c] = M[(size_t)r * C_DIM + c0 + c];
        }
        __syncthreads();
#pragma unroll
        for (int cc = 0; cc < 128; cc += 4) {
            float4 a = *(const float4*)&buf[ti][cc];
            float4 b = *(const float4*)&buf[tj][cc];
            acc += a.x * b.x + a.y * b.y + a.z * b.z + a.w * b.w;
        }
        __syncthreads();
    }
    if (ti == tj) nrm[ti] = acc;
    __syncthreads();

    const float inv_sqrtC = 1.0f / sqrtf((float)C_DIM);
    {
        float d2 = nrm[ti] + nrm[tj] - 2.f * acc;
        d2s[ti][tj] = sqrtf(fmaxf(d2, 0.f)) * inv_sqrtC;
    }
    __syncthreads();

    if (tid < CN1) {
        float m0 = 3.4e38f, m1 = 3.4e38f, m2v = 3.4e38f, mx = 0.f;
        for (int j = 0; j < CN1; j++) {
            float d = d2s[tid][j];
            mx = fmaxf(mx, d);
            if (d < m2v) {
                m2v = d;
                if (m2v < m1) { float tmp = m2v; m2v = m1; m1 = tmp; }
                if (m1 < m0)  { float tmp = m1;  m1 = m0;  m0 = tmp; }
            }
        }
        dens[tid] = expf(-(m0 * m0 + m1 * m1 + m2v * m2v) / (float)KNN2);
        rmx[tid] = mx;
    }
    __syncthreads();
    if (tid == 0) {
        float g = 0.f;
        for (int j = 0; j < CN1; j++) g = fmaxf(g, rmx[j]);
        dmax_sh = g;
    }
    __syncthreads();

    if (tid < CN1) {
        float di = dens[tid];
        float pd = dmax_sh;
        for (int j = 0; j < CN1; j++)
            if (dens[j] > di) pd = fminf(pd, d2s[tid][j]);
        scor[tid] = pd * di;
    }
    __syncthreads();

    if (tid == 0) {
        for (int k = 0; k < CN2; k++) {
            float best = -3.4e38f; int bi = 0;
            for (int j = 0; j < CN1; j++)
                if (scor[j] > best) { best = scor[j]; bi = j; }
            centers[k] = bi;
            scor[bi] = -3.4e38f;
        }
    }
    __syncthreads();

    if (tid < CN1) {
        float bd = 3.4e38f; int bk = 0;
#pragma unroll
        for (int k = 0; k < CN2; k++) {
            float d = d2s[centers[k]][tid];
            if (d < bd) { bd = d; bk = k; }
        }
#pragma unroll
        for (int k = 0; k < CN2; k++) if (tid == centers[k]) bk = k;
        idx2s[tid] = bk;
    }
    __syncthreads();

    if (tid == 0) {
        for (int v = 0; v < CN2; v++) cnt2[v] = 0;
        for (int i = 0; i < CN1; i++) cnt2[idx2s[i]]++;
        int slot = 0;
        for (int v = 0; v < CN2; v++) {
            srcRow[slot] = CN1 + v; cidArr[slot] = v; slot++;
            for (int i = 0; i < CN1; i++)
                if (idx2s[i] == v) { srcRow[slot] = i; cidArr[slot] = v; slot++; }
        }
        for (int v = 0; v < CN2; v++) msum[v] = 0.f;
    }
    __syncthreads();

    float ls[CN2] = {0.f, 0.f, 0.f, 0.f, 0.f, 0.f};
    for (int ch = tid; ch < C_DIM; ch += 256) {
        float a6[CN2] = {0.f, 0.f, 0.f, 0.f, 0.f, 0.f};
        for (int r = 0; r < CN1; r++) {
            float v = M[(size_t)r * C_DIM + ch];
            int c = idx2s[r];
#pragma unroll
            for (int q = 0; q < CN2; q++) a6[q] += (c == q) ? v : 0.f;
        }
#pragma unroll
        for (int q = 0; q < CN2; q++) {
            float mv = a6[q] / ((float)cnt2[q] + 1e-6f);
            m2[q][ch] = mv;
            ls[q] += mv;
        }
    }
#pragma unroll
    for (int q = 0; q < CN2; q++) atomicAdd(&msum[q], ls[q]);
    __syncthreads();

    if (tid == 0) {
        float mean[CN2], lg[CN2];
        for (int v = 0; v < CN2; v++) mean[v] = msum[v] / (float)C_DIM;
        float mxl = -3.4e38f;
        for (int u = 0; u < CN2; u++) {
            float s = score_b[u];
            for (int v = 0; v < CN2; v++) s += mean[v] * score_w[u * CN2 + v];
            lg[u] = s;
            mxl = fmaxf(mxl, s);
        }
        float den = 0.f;
        for (int u = 0; u < CN2; u++) { lg[u] = expf(lg[u] - mxl); den += lg[u]; }
        for (int u = 0; u < CN2; u++) modu[u] = lg[u] / den;
    }
    __syncthreads();

    float* ob = out + (size_t)t * NOUT * C_DIM;
    for (int ch = tid; ch < C_DIM; ch += 256) {
#pragma unroll
        for (int s = 0; s < NOUT; s++) {
            int r = srcRow[s];
            float v = (r < CN1) ? M[(size_t)r * C_DIM + ch] : m2[r - CN1][ch];
            ob[(size_t)s * C_DIM + ch] = v * modu[cidArr[s]];
        }
    }
}

// ---------------------------------------------------------------------------
extern "C" void kernel_launch(void* const* d_in, const int* in_sizes, int n_in,
                              void* d_out, int out_size, void* d_ws, size_t ws_size,
                              hipStream_t stream) {
    const float* x  = (const float*)d_in[0];   // [128,256,1408]
    const float* sw = (const float*)d_in[1];   // [6,6]
    const float* sb = (const float*)d_in[2];   // [6]
    float* out = (float*)d_out;                // [128,22,1408]

    float* ws     = (float*)d_ws;
    float* dist   = ws;                                          // 33,554,432 f
    float* meta1  = dist + (size_t)T_BATCH * N_TOK * N_TOK;      // 2,883,584 f
    float* dens   = meta1 + (size_t)T_BATCH * CN1 * C_DIM;       // 32768 f
    float* score  = dens + (size_t)T_BATCH * N_TOK;              // 32768 f
    int*   memb   = (int*)(score + (size_t)T_BATCH * N_TOK);     // 32768 i
    int*   cntg   = memb + (size_t)T_BATCH * N_TOK;              // 2048 i
    int*   offg   = cntg + T_BATCH * CN1;                        // 2048 i
    unsigned* dmax = (unsigned*)(offg + T_BATCH * CN1);          // 128 u

    (void)hipMemsetAsync(dmax, 0, T_BATCH * sizeof(unsigned), stream);
    gemm_dist_mfma<<<dim3(2, 2, T_BATCH), 256, 0, stream>>>(x, dist);
    density_kernel<<<dim3(4, T_BATCH), 64, 0, stream>>>(dist, dens, dmax);
    score_kernel<<<dim3(4, T_BATCH), 64, 0, stream>>>(dist, dens, dmax, score);
    topk_assign_kernel<<<T_BATCH, 256, 0, stream>>>(dist, score, memb, cntg, offg);
    merge1_kernel<<<dim3(CN1, T_BATCH), 256, 0, stream>>>(x, memb, cntg, offg, meta1);
    layer2_kernel<<<T_BATCH, 256, 0, stream>>>(meta1, sw, sb, out);
}

// Round 5
// 487.521 us; speedup vs baseline: 1.9119x; 1.0337x over previous
//
#include <hip/hip_runtime.h>
#include <math.h>

#define T_BATCH 128
#define N_TOK   256
#define C_DIM   1408
#define CN1     16
#define KNN1    8
#define CN2     6
#define KNN2    3
#define NOUT    22   // CN2 + CN1
#define LSTR    40   // LDS row stride in shorts (80 B), 16B-aligned rows

typedef __attribute__((ext_vector_type(4))) short sh4;
typedef __attribute__((ext_vector_type(8))) short sh8;
typedef __attribute__((ext_vector_type(4))) float f32x4;

union frag_u { sh4 h[2]; sh8 v; };

__device__ inline sh8 ld_frag(const short* p) {
    frag_u u;
    u.h[0] = *(const sh4*)p;
    u.h[1] = *(const sh4*)(p + 4);
    return u.v;
}

// truncation split of a PAIR of fp32 -> packed bf16 hi pair + RNE bf16 lo pair.
// hi = bit-truncated (toward zero); lo = RNE(v - hi). Error on dot ~2e-7 rel.
__device__ inline void split2(float v0, float v1, unsigned& hip, unsigned& lop) {
    unsigned u0 = __float_as_uint(v0);
    unsigned u1 = __float_as_uint(v1);
    hip = (u0 >> 16) | (u1 & 0xFFFF0000u);
    float l0 = v0 - __uint_as_float(u0 & 0xFFFF0000u);
    float l1 = v1 - __uint_as_float(u1 & 0xFFFF0000u);
    unsigned w0 = __float_as_uint(l0);
    unsigned w1 = __float_as_uint(l1);
    w0 = w0 + 0x7FFFu + ((w0 >> 16) & 1u);
    w1 = w1 + 0x7FFFu + ((w1 >> 16) & 1u);
    lop = (w0 >> 16) | (w1 & 0xFFFF0000u);
}

// ---------------------------------------------------------------------------
// Kernel A: dist via bf16x3 MFMA (hi*hi + hi*lo + lo*hi), 128x128 tile/block.
// Diagonal blocks (i0==j0) stage/split only A and alias B to it.
// Row norms fused. D = sqrt(max(sq_i+sq_j-2*dot,0))/sqrt(C), diag forced 0.
// ---------------------------------------------------------------------------
__global__ __launch_bounds__(256, 3) void gemm_dist_mfma(const float* __restrict__ x,
                                                         float* __restrict__ dist) {
    const int t  = blockIdx.z;
    const int i0 = blockIdx.x * 128;
    const int j0 = blockIdx.y * 128;
    const bool diag = (i0 == j0);
    const float* X = x + (size_t)t * N_TOK * C_DIM;

    __shared__ short Ahi[128 * LSTR], Alo[128 * LSTR], Bhi[128 * LSTR], Blo[128 * LSTR];
    __shared__ float nredA[256], nredB[256];
    __shared__ float snA[128], snB[128];

    const int tid  = threadIdx.x;
    const int wave = tid >> 6;
    const int lane = tid & 63;
    const int qr   = wave >> 1;        // wave row half (0/1)
    const int qc   = wave & 1;         // wave col half (0/1)
    const int srow = tid >> 1;         // staging row 0..127
    const int scol = (tid & 1) * 16;   // staging col group 0 or 16
    const int fr   = lane & 15;
    const int fq   = lane >> 4;        // k offset fq*8

    const short* BhiS = diag ? Ahi : Bhi;
    const short* BloS = diag ? Alo : Blo;

    f32x4 acc[4][4];
#pragma unroll
    for (int a = 0; a < 4; a++)
#pragma unroll
        for (int b = 0; b < 4; b++) acc[a][b] = (f32x4){0.f, 0.f, 0.f, 0.f};

    const float* Arow = X + (size_t)(i0 + srow) * C_DIM + scol;
    const float* Brow = X + (size_t)(j0 + srow) * C_DIM + scol;
    float nA = 0.f, nB = 0.f;

    for (int k0 = 0; k0 < C_DIM; k0 += 32) {
        float av[16], bv[16];
#pragma unroll
        for (int g = 0; g < 4; g++) {
            float4 a = *(const float4*)(Arow + k0 + g * 4);
            av[g * 4 + 0] = a.x; av[g * 4 + 1] = a.y; av[g * 4 + 2] = a.z; av[g * 4 + 3] = a.w;
        }
#pragma unroll
        for (int e = 0; e < 16; e++) nA += av[e] * av[e];
        if (!diag) {
#pragma unroll
            for (int g = 0; g < 4; g++) {
                float4 b = *(const float4*)(Brow + k0 + g * 4);
                bv[g * 4 + 0] = b.x; bv[g * 4 + 1] = b.y; bv[g * 4 + 2] = b.z; bv[g * 4 + 3] = b.w;
            }
#pragma unroll
            for (int e = 0; e < 16; e++) nB += bv[e] * bv[e];
        }

        unsigned ah[8], al[8], bh[8], bl[8];
#pragma unroll
        for (int p = 0; p < 8; p++) split2(av[2 * p], av[2 * p + 1], ah[p], al[p]);
        if (!diag) {
#pragma unroll
            for (int p = 0; p < 8; p++) split2(bv[2 * p], bv[2 * p + 1], bh[p], bl[p]);
        }
        __syncthreads();
        unsigned* AhiW = (unsigned*)&Ahi[srow * LSTR + scol];
        unsigned* AloW = (unsigned*)&Alo[srow * LSTR + scol];
#pragma unroll
        for (int p = 0; p < 8; p++) { AhiW[p] = ah[p]; AloW[p] = al[p]; }
        if (!diag) {
            unsigned* BhiW = (unsigned*)&Bhi[srow * LSTR + scol];
            unsigned* BloW = (unsigned*)&Blo[srow * LSTR + scol];
#pragma unroll
            for (int p = 0; p < 8; p++) { BhiW[p] = bh[p]; BloW[p] = bl[p]; }
        }
        __syncthreads();

        sh8 fAh[4], fAl[4], fBh[4], fBl[4];
#pragma unroll
        for (int mt = 0; mt < 4; mt++) {
            int ro = (qr * 64 + mt * 16 + fr) * LSTR + fq * 8;
            fAh[mt] = ld_frag(&Ahi[ro]);
            fAl[mt] = ld_frag(&Alo[ro]);
            int co = (qc * 64 + mt * 16 + fr) * LSTR + fq * 8;
            fBh[mt] = ld_frag(&BhiS[co]);
            fBl[mt] = ld_frag(&BloS[co]);
        }
#pragma unroll
        for (int mt = 0; mt < 4; mt++)
#pragma unroll
            for (int nt = 0; nt < 4; nt++) {
                acc[mt][nt] = __builtin_amdgcn_mfma_f32_16x16x32_bf16(fAh[mt], fBh[nt], acc[mt][nt], 0, 0, 0);
                acc[mt][nt] = __builtin_amdgcn_mfma_f32_16x16x32_bf16(fAh[mt], fBl[nt], acc[mt][nt], 0, 0, 0);
                acc[mt][nt] = __builtin_amdgcn_mfma_f32_16x16x32_bf16(fAl[mt], fBh[nt], acc[mt][nt], 0, 0, 0);
            }
    }

    nredA[tid] = nA;
    nredB[tid] = diag ? nA : nB;
    __syncthreads();
    if (tid < 128) {
        snA[tid] = nredA[2 * tid] + nredA[2 * tid + 1];
        snB[tid] = nredB[2 * tid] + nredB[2 * tid + 1];
    }
    __syncthreads();

    const float inv_sqrtC = 1.0f / sqrtf((float)C_DIM);
    float* Dt = dist + (size_t)t * N_TOK * N_TOK;
#pragma unroll
    for (int mt = 0; mt < 4; mt++)
#pragma unroll
        for (int nt = 0; nt < 4; nt++) {
            int jl = qc * 64 + nt * 16 + fr;
            float sqj = snB[jl];
            int jg = j0 + jl;
#pragma unroll
            for (int r = 0; r < 4; r++) {
                int il = qr * 64 + mt * 16 + fq * 4 + r;
                int ig = i0 + il;
                float d2 = snA[il] + sqj - 2.0f * acc[mt][nt][r];
                float v = (ig == jg) ? 0.0f : sqrtf(fmaxf(d2, 0.0f)) * inv_sqrtC;
                Dt[(size_t)ig * N_TOK + jg] = v;
            }
        }
}

// ---------------------------------------------------------------------------
// Kernel B: fused layer-1 DPC. One block (256 threads) per batch.
// pass1: knn density (thread = column, insertion sort) + block max.
// pass2: parent dist + score. Then top-16, assignment, member lists.
// ---------------------------------------------------------------------------
__global__ __launch_bounds__(256) void dpc1_fused(const float* __restrict__ dist,
                                                  int* __restrict__ memb,
                                                  int* __restrict__ cntg,
                                                  int* __restrict__ offg) {
    const int t   = blockIdx.x;
    const int tid = threadIdx.x;
    const float* D = dist + (size_t)t * N_TOK * N_TOK;

    __shared__ float dens_s[N_TOK];
    __shared__ float red[N_TOK];
    __shared__ unsigned long long wbest[4];
    __shared__ int centers[CN1];
    __shared__ int bks[N_TOK];
    __shared__ int cnt_s[CN1], off_s[CN1];

    // ---- pass 1: k=8 smallest of column tid (symmetry: col == row to 1 ulp) ----
    float m[KNN1];
#pragma unroll
    for (int q = 0; q < KNN1; q++) m[q] = 3.4e38f;
    float mx = 0.f;
#pragma unroll 8
    for (int j = 0; j < N_TOK; j++) {
        float d = D[(size_t)j * N_TOK + tid];
        mx = fmaxf(mx, d);
        float xv = d;
#pragma unroll
        for (int q = 0; q < KNN1; q++) {
            float lo = fminf(m[q], xv);
            xv = fmaxf(m[q], xv);
            m[q] = lo;
        }
    }
    float s2 = 0.f;
#pragma unroll
    for (int q = 0; q < KNN1; q++) s2 += m[q] * m[q];
    float dens = expf(-s2 / (float)KNN1);
    dens_s[tid] = dens;
    red[tid] = mx;
    __syncthreads();
#pragma unroll
    for (int s = 128; s > 0; s >>= 1) {
        if (tid < s) red[tid] = fmaxf(red[tid], red[tid + s]);
        __syncthreads();
    }
    float dmax = red[0];

    // ---- pass 2: parent distance (min dist to strictly denser) ----
    float pd = dmax;
#pragma unroll 8
    for (int j = 0; j < N_TOK; j++) {
        float d = D[(size_t)j * N_TOK + tid];
        float dj = dens_s[j];
        pd = (dj > dens) ? fminf(pd, d) : pd;
    }
    float score = pd * dens;

    // ---- top-16 (desc, ties -> lowest index) ----
    unsigned long long key = ((unsigned long long)__float_as_uint(score) << 32)
                           | (unsigned)(65535 - tid);
    for (int k = 0; k < CN1; k++) {
        unsigned long long mm = key;
#pragma unroll
        for (int off = 32; off > 0; off >>= 1) {
            unsigned long long o = __shfl_xor(mm, off);
            mm = (o > mm) ? o : mm;
        }
        if ((tid & 63) == 0) wbest[tid >> 6] = mm;
        __syncthreads();
        unsigned long long b = wbest[0];
#pragma unroll
        for (int w = 1; w < 4; w++) b = (wbest[w] > b) ? wbest[w] : b;
        int idx = 65535 - (int)(b & 0xFFFFull);
        if (tid == 0) centers[k] = idx;
        if (tid == idx) key = 0;
        __syncthreads();
    }

    // ---- assign to nearest center (first-min), centers override ----
    float bd = 3.4e38f; int bk = 0;
#pragma unroll
    for (int k = 0; k < CN1; k++) {
        float d = D[(size_t)centers[k] * N_TOK + tid];
        if (d < bd) { bd = d; bk = k; }
    }
#pragma unroll
    for (int k = 0; k < CN1; k++) if (tid == centers[k]) bk = k;

    // ---- member lists (ascending token order per cluster) ----
    bks[tid] = bk;
    __syncthreads();
    if (tid < CN1) {
        int c = 0;
        for (int j = 0; j < N_TOK; j++) c += (bks[j] == tid);
        cnt_s[tid] = c;
    }
    __syncthreads();
    if (tid == 0) {
        int o = 0;
        for (int q = 0; q < CN1; q++) { off_s[q] = o; o += cnt_s[q]; }
    }
    __syncthreads();
    int rank = 0;
    for (int j = 0; j < tid; j++) rank += (bks[j] == bk);
    memb[t * N_TOK + off_s[bk] + rank] = tid;
    if (tid < CN1) {
        cntg[t * CN1 + tid] = cnt_s[tid];
        offg[t * CN1 + tid] = off_s[tid];
    }
}

// ---------------------------------------------------------------------------
// Kernel C: merge1 via member lists. Block (cluster q, batch t).
// ---------------------------------------------------------------------------
__global__ __launch_bounds__(256) void merge1_kernel(const float* __restrict__ x,
                                                     const int* __restrict__ memb,
                                                     const int* __restrict__ cntg,
                                                     const int* __restrict__ offg,
                                                     float* __restrict__ meta1) {
    const int q   = blockIdx.x;
    const int t   = blockIdx.y;
    const int tid = threadIdx.x;
    const int n    = cntg[t * CN1 + q];
    const int base = t * N_TOK + offg[t * CN1 + q];
    const int c0 = tid, c1 = tid + 256;        // float4 indices; 352 per row
    const bool act1 = (c1 < C_DIM / 4);

    float a0x = 0.f, a0y = 0.f, a0z = 0.f, a0w = 0.f;
    float a1x = 0.f, a1y = 0.f, a1z = 0.f, a1w = 0.f;
    for (int m = 0; m < n; m++) {
        int row = memb[base + m];
        const float4* xr = (const float4*)(x + ((size_t)t * N_TOK + row) * C_DIM);
        float4 v0 = xr[c0];
        a0x += v0.x; a0y += v0.y; a0z += v0.z; a0w += v0.w;
        if (act1) {
            float4 v1 = xr[c1];
            a1x += v1.x; a1y += v1.y; a1z += v1.z; a1w += v1.w;
        }
    }
    float w = 1.0f / ((float)n + 1e-6f);
    float4* mr = (float4*)(meta1 + ((size_t)t * CN1 + q) * C_DIM);
    float4 o0; o0.x = a0x * w; o0.y = a0y * w; o0.z = a0z * w; o0.w = a0w * w;
    mr[c0] = o0;
    if (act1) {
        float4 o1; o1.x = a1x * w; o1.y = a1y * w; o1.z = a1z * w; o1.w = a1w * w;
        mr[c1] = o1;
    }
}

// ---------------------------------------------------------------------------
// Kernel DE: layer-2 DPC + merge2 + modulation + grouped output.
// One block (256 threads) per batch.
// ---------------------------------------------------------------------------
__global__ __launch_bounds__(256) void layer2_kernel(const float* __restrict__ meta1,
                                                     const float* __restrict__ score_w,
                                                     const float* __restrict__ score_b,
                                                     float* __restrict__ out) {
    const int t   = blockIdx.x;
    const int tid = threadIdx.x;
    const float* M = meta1 + (size_t)t * CN1 * C_DIM;

    __shared__ float buf[CN1][132];
    __shared__ float d2s[CN1][CN1];
    __shared__ float m2[CN2][C_DIM];
    __shared__ float dens[CN1], scor[CN1], nrm[CN1], rmx[CN1];
    __shared__ int   centers[CN2], idx2s[CN1], cnt2[CN2];
    __shared__ float modu[CN2], msum[CN2];
    __shared__ int   srcRow[NOUT], cidArr[NOUT];
    __shared__ float dmax_sh;

    const int ti = tid >> 4;
    const int tj = tid & 15;

    float acc = 0.f;
    for (int c0 = 0; c0 < C_DIM; c0 += 128) {
        for (int e = tid; e < CN1 * 128; e += 256) {
            int r = e >> 7, c = e & 127;
            buf[r][c] = M[(size_t)r * C_DIM + c0 + c];
        }
        __syncthreads();
#pragma unroll
        for (int cc = 0; cc < 128; cc += 4) {
            float4 a = *(const float4*)&buf[ti][cc];
            float4 b = *(const float4*)&buf[tj][cc];
            acc += a.x * b.x + a.y * b.y + a.z * b.z + a.w * b.w;
        }
        __syncthreads();
    }
    if (ti == tj) nrm[ti] = acc;
    __syncthreads();

    const float inv_sqrtC = 1.0f / sqrtf((float)C_DIM);
    {
        float d2 = nrm[ti] + nrm[tj] - 2.f * acc;
        d2s[ti][tj] = sqrtf(fmaxf(d2, 0.f)) * inv_sqrtC;
    }
    __syncthreads();

    if (tid < CN1) {
        float m0 = 3.4e38f, m1 = 3.4e38f, m2v = 3.4e38f, mx = 0.f;
        for (int j = 0; j < CN1; j++) {
            float d = d2s[tid][j];
            mx = fmaxf(mx, d);
            if (d < m2v) {
                m2v = d;
                if (m2v < m1) { float tmp = m2v; m2v = m1; m1 = tmp; }
                if (m1 < m0)  { float tmp = m1;  m1 = m0;  m0 = tmp; }
            }
        }
        dens[tid] = expf(-(m0 * m0 + m1 * m1 + m2v * m2v) / (float)KNN2);
        rmx[tid] = mx;
    }
    __syncthreads();
    if (tid == 0) {
        float g = 0.f;
        for (int j = 0; j < CN1; j++) g = fmaxf(g, rmx[j]);
        dmax_sh = g;
    }
    __syncthreads();

    if (tid < CN1) {
        float di = dens[tid];
        float pd = dmax_sh;
        for (int j = 0; j < CN1; j++)
            if (dens[j] > di) pd = fminf(pd, d2s[tid][j]);
        scor[tid] = pd * di;
    }
    __syncthreads();

    if (tid == 0) {
        for (int k = 0; k < CN2; k++) {
            float best = -3.4e38f; int bi = 0;
            for (int j = 0; j < CN1; j++)
                if (scor[j] > best) { best = scor[j]; bi = j; }
            centers[k] = bi;
            scor[bi] = -3.4e38f;
        }
    }
    __syncthreads();

    if (tid < CN1) {
        float bd = 3.4e38f; int bk = 0;
#pragma unroll
        for (int k = 0; k < CN2; k++) {
            float d = d2s[centers[k]][tid];
            if (d < bd) { bd = d; bk = k; }
        }
#pragma unroll
        for (int k = 0; k < CN2; k++) if (tid == centers[k]) bk = k;
        idx2s[tid] = bk;
    }
    __syncthreads();

    if (tid == 0) {
        for (int v = 0; v < CN2; v++) cnt2[v] = 0;
        for (int i = 0; i < CN1; i++) cnt2[idx2s[i]]++;
        int slot = 0;
        for (int v = 0; v < CN2; v++) {
            srcRow[slot] = CN1 + v; cidArr[slot] = v; slot++;
            for (int i = 0; i < CN1; i++)
                if (idx2s[i] == v) { srcRow[slot] = i; cidArr[slot] = v; slot++; }
        }
        for (int v = 0; v < CN2; v++) msum[v] = 0.f;
    }
    __syncthreads();

    float ls[CN2] = {0.f, 0.f, 0.f, 0.f, 0.f, 0.f};
    for (int ch = tid; ch < C_DIM; ch += 256) {
        float a6[CN2] = {0.f, 0.f, 0.f, 0.f, 0.f, 0.f};
        for (int r = 0; r < CN1; r++) {
            float v = M[(size_t)r * C_DIM + ch];
            int c = idx2s[r];
#pragma unroll
            for (int q = 0; q < CN2; q++) a6[q] += (c == q) ? v : 0.f;
        }
#pragma unroll
        for (int q = 0; q < CN2; q++) {
            float mv = a6[q] / ((float)cnt2[q] + 1e-6f);
            m2[q][ch] = mv;
            ls[q] += mv;
        }
    }
#pragma unroll
    for (int q = 0; q < CN2; q++) atomicAdd(&msum[q], ls[q]);
    __syncthreads();

    if (tid == 0) {
        float mean[CN2], lg[CN2];
        for (int v = 0; v < CN2; v++) mean[v] = msum[v] / (float)C_DIM;
        float mxl = -3.4e38f;
        for (int u = 0; u < CN2; u++) {
            float s = score_b[u];
            for (int v = 0; v < CN2; v++) s += mean[v] * score_w[u * CN2 + v];
            lg[u] = s;
            mxl = fmaxf(mxl, s);
        }
        float den = 0.f;
        for (int u = 0; u < CN2; u++) { lg[u] = expf(lg[u] - mxl); den += lg[u]; }
        for (int u = 0; u < CN2; u++) modu[u] = lg[u] / den;
    }
    __syncthreads();

    float* ob = out + (size_t)t * NOUT * C_DIM;
    for (int ch = tid; ch < C_DIM; ch += 256) {
#pragma unroll
        for (int s = 0; s < NOUT; s++) {
            int r = srcRow[s];
            float v = (r < CN1) ? M[(size_t)r * C_DIM + ch] : m2[r - CN1][ch];
            ob[(size_t)s * C_DIM + ch] = v * modu[cidArr[s]];
        }
    }
}

// ---------------------------------------------------------------------------
extern "C" void kernel_launch(void* const* d_in, const int* in_sizes, int n_in,
                              void* d_out, int out_size, void* d_ws, size_t ws_size,
                              hipStream_t stream) {
    const float* x  = (const float*)d_in[0];   // [128,256,1408]
    const float* sw = (const float*)d_in[1];   // [6,6]
    const float* sb = (const float*)d_in[2];   // [6]
    float* out = (float*)d_out;                // [128,22,1408]

    float* ws     = (float*)d_ws;
    float* dist   = ws;                                          // 8,388,608 f
    float* meta1  = dist + (size_t)T_BATCH * N_TOK * N_TOK;      // 2,883,584 f
    int*   memb   = (int*)(meta1 + (size_t)T_BATCH * CN1 * C_DIM); // 32768 i
    int*   cntg   = memb + (size_t)T_BATCH * N_TOK;              // 2048 i
    int*   offg   = cntg + T_BATCH * CN1;                        // 2048 i

    gemm_dist_mfma<<<dim3(2, 2, T_BATCH), 256, 0, stream>>>(x, dist);
    dpc1_fused<<<T_BATCH, 256, 0, stream>>>(dist, memb, cntg, offg);
    merge1_kernel<<<dim3(CN1, T_BATCH), 256, 0, stream>>>(x, memb, cntg, offg, meta1);
    layer2_kernel<<<T_BATCH, 256, 0, stream>>>(meta1, sw, sb, out);
}

// Round 6
// 443.861 us; speedup vs baseline: 2.1000x; 1.0984x over previous
//
#include <hip/hip_runtime.h>
#include <math.h>

#define T_BATCH 128
#define N_TOK   256
#define C_DIM   1408
#define CN1     16
#define KNN1    8
#define CN2     6
#define KNN2    3
#define NOUT    22   // CN2 + CN1
#define LS      44   // LDS row stride in shorts (22 words: odd-free 2-3-way banks, 8B-aligned)

typedef __attribute__((ext_vector_type(4))) short sh4;
typedef __attribute__((ext_vector_type(8))) short sh8;
typedef __attribute__((ext_vector_type(4))) float f32x4;

union frag_u { sh4 h[2]; sh8 v; };

__device__ inline sh8 ld_frag(const short* p) {
    frag_u u;
    u.h[0] = *(const sh4*)p;
    u.h[1] = *(const sh4*)(p + 4);
    return u.v;
}

// truncation split of a PAIR of fp32 -> packed bf16 hi pair + RNE bf16 lo pair.
__device__ inline void split2(float v0, float v1, unsigned& hip, unsigned& lop) {
    unsigned u0 = __float_as_uint(v0);
    unsigned u1 = __float_as_uint(v1);
    hip = (u0 >> 16) | (u1 & 0xFFFF0000u);
    float l0 = v0 - __uint_as_float(u0 & 0xFFFF0000u);
    float l1 = v1 - __uint_as_float(u1 & 0xFFFF0000u);
    unsigned w0 = __float_as_uint(l0);
    unsigned w1 = __float_as_uint(l1);
    w0 = w0 + 0x7FFFu + ((w0 >> 16) & 1u);
    w1 = w1 + 0x7FFFu + ((w1 >> 16) & 1u);
    lop = (w0 >> 16) | (w1 & 0xFFFF0000u);
}

// branchless insert of v into ascending 8-list m (keeps 8 smallest)
#define INS8(m, v) {                                   \
    float _x = (v);                                    \
    _Pragma("unroll")                                  \
    for (int _q = 0; _q < 8; _q++) {                   \
        float _lo = fminf(m[_q], _x);                  \
        _x = fmaxf(m[_q], _x);                         \
        m[_q] = _lo;                                   \
    }                                                  \
}

// ---------------------------------------------------------------------------
// Kernel A: dist via bf16x3 MFMA, 64x64 tiles, SYMMETRY: only upper-tri block
// pairs (10 per batch). Off-diag blocks write tile + transposed tile (exact
// symmetry). Diag blocks alias B fragments to A (half the staging).
// Wave = 32x32 quadrant (2x2 of 16x16x32). Row norms fused.
// ---------------------------------------------------------------------------
__global__ __launch_bounds__(256, 4) void gemm_dist_sym(const float* __restrict__ x,
                                                        float* __restrict__ dist) {
    const int t = blockIdx.y;
    const int p = blockIdx.x;
    const int bi = (p < 4) ? 0 : (p < 7) ? 1 : (p < 9) ? 2 : 3;
    const int bj = (p < 4) ? p : (p < 7) ? p - 3 : (p < 9) ? p - 5 : 3;
    const int i0 = bi * 64, j0 = bj * 64;
    const bool diag = (bi == bj);
    const float* X = x + (size_t)t * N_TOK * C_DIM;

    __shared__ short Ahi[64 * LS], Alo[64 * LS], Bhi[64 * LS], Blo[64 * LS];
    __shared__ float nred[512];
    __shared__ float snA[64], snB[64];

    const int tid  = threadIdx.x;
    const int wave = tid >> 6;
    const int lane = tid & 63;
    const int qr   = wave >> 1;       // 32-row half
    const int qc   = wave & 1;        // 32-col half
    const int srow = tid >> 2;        // staging row 0..63
    const int sq   = tid & 3;         // staging 8-short unit
    const int fr   = lane & 15;
    const int fq   = lane >> 4;

    const short* BhiS = diag ? Ahi : Bhi;
    const short* BloS = diag ? Alo : Blo;

    f32x4 acc[2][2];
#pragma unroll
    for (int a = 0; a < 2; a++)
#pragma unroll
        for (int b = 0; b < 2; b++) acc[a][b] = (f32x4){0.f, 0.f, 0.f, 0.f};

    const float* Arow = X + (size_t)(i0 + srow) * C_DIM + sq * 8;
    const float* Brow = X + (size_t)(j0 + srow) * C_DIM + sq * 8;
    float nA = 0.f, nB = 0.f;

    for (int k0 = 0; k0 < C_DIM; k0 += 32) {
        float av[8], bv[8];
        float4 a0 = *(const float4*)(Arow + k0);
        float4 a1 = *(const float4*)(Arow + k0 + 4);
        av[0] = a0.x; av[1] = a0.y; av[2] = a0.z; av[3] = a0.w;
        av[4] = a1.x; av[5] = a1.y; av[6] = a1.z; av[7] = a1.w;
#pragma unroll
        for (int e = 0; e < 8; e++) nA += av[e] * av[e];
        unsigned ah[4], al[4], bh[4], bl[4];
#pragma unroll
        for (int q = 0; q < 4; q++) split2(av[2 * q], av[2 * q + 1], ah[q], al[q]);
        if (!diag) {
            float4 b0 = *(const float4*)(Brow + k0);
            float4 b1 = *(const float4*)(Brow + k0 + 4);
            bv[0] = b0.x; bv[1] = b0.y; bv[2] = b0.z; bv[3] = b0.w;
            bv[4] = b1.x; bv[5] = b1.y; bv[6] = b1.z; bv[7] = b1.w;
#pragma unroll
            for (int e = 0; e < 8; e++) nB += bv[e] * bv[e];
#pragma unroll
            for (int q = 0; q < 4; q++) split2(bv[2 * q], bv[2 * q + 1], bh[q], bl[q]);
        }
        __syncthreads();
        {
            unsigned* AH = (unsigned*)&Ahi[srow * LS + sq * 8];
            unsigned* AL = (unsigned*)&Alo[srow * LS + sq * 8];
#pragma unroll
            for (int q = 0; q < 4; q++) { AH[q] = ah[q]; AL[q] = al[q]; }
            if (!diag) {
                unsigned* BH = (unsigned*)&Bhi[srow * LS + sq * 8];
                unsigned* BL = (unsigned*)&Blo[srow * LS + sq * 8];
#pragma unroll
                for (int q = 0; q < 4; q++) { BH[q] = bh[q]; BL[q] = bl[q]; }
            }
        }
        __syncthreads();

        sh8 fAh[2], fAl[2], fBh[2], fBl[2];
#pragma unroll
        for (int mt = 0; mt < 2; mt++) {
            int ro = (qr * 32 + mt * 16 + fr) * LS + fq * 8;
            fAh[mt] = ld_frag(&Ahi[ro]);
            fAl[mt] = ld_frag(&Alo[ro]);
            int co = (qc * 32 + mt * 16 + fr) * LS + fq * 8;
            fBh[mt] = ld_frag(&BhiS[co]);
            fBl[mt] = ld_frag(&BloS[co]);
        }
#pragma unroll
        for (int mt = 0; mt < 2; mt++)
#pragma unroll
            for (int nt = 0; nt < 2; nt++) {
                acc[mt][nt] = __builtin_amdgcn_mfma_f32_16x16x32_bf16(fAh[mt], fBh[nt], acc[mt][nt], 0, 0, 0);
                acc[mt][nt] = __builtin_amdgcn_mfma_f32_16x16x32_bf16(fAh[mt], fBl[nt], acc[mt][nt], 0, 0, 0);
                acc[mt][nt] = __builtin_amdgcn_mfma_f32_16x16x32_bf16(fAl[mt], fBh[nt], acc[mt][nt], 0, 0, 0);
            }
    }

    nred[tid] = nA;
    nred[256 + tid] = diag ? nA : nB;
    __syncthreads();
    if (tid < 64) {
        snA[tid] = nred[4 * tid] + nred[4 * tid + 1] + nred[4 * tid + 2] + nred[4 * tid + 3];
        snB[tid] = nred[256 + 4 * tid] + nred[256 + 4 * tid + 1]
                 + nred[256 + 4 * tid + 2] + nred[256 + 4 * tid + 3];
    }
    __syncthreads();

    const float inv_sqrtC = 1.0f / sqrtf((float)C_DIM);
    float* Dt = dist + (size_t)t * N_TOK * N_TOK;
#pragma unroll
    for (int mt = 0; mt < 2; mt++)
#pragma unroll
        for (int nt = 0; nt < 2; nt++) {
            int jl = qc * 32 + nt * 16 + fr;
            int jg = j0 + jl;
            float sqj = snB[jl];
            int il0 = qr * 32 + mt * 16 + fq * 4;
            float vv[4];
#pragma unroll
            for (int r = 0; r < 4; r++) {
                int ig = i0 + il0 + r;
                float d2 = snA[il0 + r] + sqj - 2.0f * acc[mt][nt][r];
                float v = (ig == jg) ? 0.0f : sqrtf(fmaxf(d2, 0.0f)) * inv_sqrtC;
                Dt[(size_t)ig * N_TOK + jg] = v;
                vv[r] = v;
            }
            if (!diag) {
                float4 o; o.x = vv[0]; o.y = vv[1]; o.z = vv[2]; o.w = vv[3];
                *(float4*)&Dt[(size_t)jg * N_TOK + i0 + il0] = o;   // exact transpose
            }
        }
}

// ---------------------------------------------------------------------------
// Kernel B: fused layer-1 DPC. 512 threads/block, one block per batch.
// 2 threads per column (halves of the j-scan), 4 independent insertion chains,
// LDS merge. Then top-16, assignment, member lists (tid<256 only).
// ---------------------------------------------------------------------------
__global__ __launch_bounds__(512) void dpc1_fused(const float* __restrict__ dist,
                                                  int* __restrict__ memb,
                                                  int* __restrict__ cntg,
                                                  int* __restrict__ offg) {
    const int t   = blockIdx.x;
    const int tid = threadIdx.x;     // 0..511
    const int col = tid & 255;
    const int h   = tid >> 8;        // j-half
    const float* D = dist + (size_t)t * N_TOK * N_TOK;

    __shared__ float dens_s[N_TOK];
    __shared__ float red[512];
    __shared__ float lists[KNN1][520];    // [q][tid] (pad to avoid pathological strides)
    __shared__ unsigned long long wbest[8];
    __shared__ int centers[CN1];
    __shared__ int bks[N_TOK];
    __shared__ int cnt_s[CN1], off_s[CN1];

    // ---- pass 1: 8 smallest of this half-column, 4 independent chains ----
    float c0[8], c1[8], c2[8], c3[8];
#pragma unroll
    for (int q = 0; q < 8; q++) { c0[q] = 3.4e38f; c1[q] = 3.4e38f; c2[q] = 3.4e38f; c3[q] = 3.4e38f; }
    float mx = 0.f;
    const float* base = D + (size_t)(h * 128) * N_TOK + col;
    for (int jj = 0; jj < 128; jj += 4) {
        float d0 = base[(size_t)(jj + 0) * N_TOK];
        float d1 = base[(size_t)(jj + 1) * N_TOK];
        float d2 = base[(size_t)(jj + 2) * N_TOK];
        float d3 = base[(size_t)(jj + 3) * N_TOK];
        mx = fmaxf(mx, fmaxf(fmaxf(d0, d1), fmaxf(d2, d3)));
        INS8(c0, d0); INS8(c1, d1); INS8(c2, d2); INS8(c3, d3);
    }
    // merge chains 1-3 into c0 (c0 holds this half's 8 smallest)
#pragma unroll
    for (int q = 0; q < 8; q++) { INS8(c0, c1[q]); }
#pragma unroll
    for (int q = 0; q < 8; q++) { INS8(c0, c2[q]); }
#pragma unroll
    for (int q = 0; q < 8; q++) { INS8(c0, c3[q]); }
#pragma unroll
    for (int q = 0; q < 8; q++) lists[q][tid] = c0[q];
    red[tid] = mx;
    __syncthreads();
#pragma unroll
    for (int s = 256; s > 0; s >>= 1) {
        if (tid < s) red[tid] = fmaxf(red[tid], red[tid + s]);
        __syncthreads();
    }
    const float dmax = red[0];
    __syncthreads();   // red about to be reused

    if (h == 0) {
#pragma unroll
        for (int q = 0; q < 8; q++) { float v = lists[q][col + 256]; INS8(c0, v); }
        float s2 = 0.f;
#pragma unroll
        for (int q = 0; q < 8; q++) s2 += c0[q] * c0[q];
        dens_s[col] = expf(-s2 / (float)KNN1);
    }
    __syncthreads();
    const float dens = dens_s[col];

    // ---- pass 2: parent distance over this half, 4 chains ----
    float p0 = dmax, p1 = dmax, p2 = dmax, p3 = dmax;
    const float* dsh = dens_s + h * 128;
    for (int jj = 0; jj < 128; jj += 4) {
        float d0 = base[(size_t)(jj + 0) * N_TOK];
        float d1 = base[(size_t)(jj + 1) * N_TOK];
        float d2 = base[(size_t)(jj + 2) * N_TOK];
        float d3 = base[(size_t)(jj + 3) * N_TOK];
        p0 = (dsh[jj + 0] > dens) ? fminf(p0, d0) : p0;
        p1 = (dsh[jj + 1] > dens) ? fminf(p1, d1) : p1;
        p2 = (dsh[jj + 2] > dens) ? fminf(p2, d2) : p2;
        p3 = (dsh[jj + 3] > dens) ? fminf(p3, d3) : p3;
    }
    red[tid] = fminf(fminf(p0, p1), fminf(p2, p3));
    __syncthreads();
    float score = 0.f;
    if (h == 0) score = fminf(red[col], red[col + 256]) * dens;

    // ---- top-16 (desc, ties -> lowest index) ----
    unsigned long long key = 0;
    if (h == 0)
        key = ((unsigned long long)__float_as_uint(score) << 32) | (unsigned)(65535 - col);
    for (int k = 0; k < CN1; k++) {
        unsigned long long mm = key;
#pragma unroll
        for (int off = 32; off > 0; off >>= 1) {
            unsigned long long o = __shfl_xor(mm, off);
            mm = (o > mm) ? o : mm;
        }
        if ((tid & 63) == 0) wbest[tid >> 6] = mm;
        __syncthreads();
        unsigned long long b = wbest[0];
#pragma unroll
        for (int w = 1; w < 8; w++) b = (wbest[w] > b) ? wbest[w] : b;
        int idx = 65535 - (int)(b & 0xFFFFull);
        if (tid == 0) centers[k] = idx;
        if (tid == idx) key = 0;   // h==0 threads have tid==col
        __syncthreads();
    }

    // ---- assign + member lists (tid<256 only; barriers unconditional) ----
    int bk = 0;
    if (h == 0) {
        float bd = 3.4e38f;
#pragma unroll
        for (int k = 0; k < CN1; k++) {
            float d = D[(size_t)centers[k] * N_TOK + col];
            if (d < bd) { bd = d; bk = k; }
        }
#pragma unroll
        for (int k = 0; k < CN1; k++) if (col == centers[k]) bk = k;
        bks[col] = bk;
    }
    __syncthreads();
    if (tid < CN1) {
        int c = 0;
        for (int j = 0; j < N_TOK; j++) c += (bks[j] == tid);
        cnt_s[tid] = c;
    }
    __syncthreads();
    if (tid == 0) {
        int o = 0;
        for (int q = 0; q < CN1; q++) { off_s[q] = o; o += cnt_s[q]; }
    }
    __syncthreads();
    if (h == 0) {
        int rank = 0;
        for (int j = 0; j < col; j++) rank += (bks[j] == bk);
        memb[t * N_TOK + off_s[bk] + rank] = col;
    }
    if (tid < CN1) {
        cntg[t * CN1 + tid] = cnt_s[tid];
        offg[t * CN1 + tid] = off_s[tid];
    }
}

// ---------------------------------------------------------------------------
// Kernel C: merge1 via member lists. Block (cluster q, batch t).
// ---------------------------------------------------------------------------
__global__ __launch_bounds__(256) void merge1_kernel(const float* __restrict__ x,
                                                     const int* __restrict__ memb,
                                                     const int* __restrict__ cntg,
                                                     const int* __restrict__ offg,
                                                     float* __restrict__ meta1) {
    const int q   = blockIdx.x;
    const int t   = blockIdx.y;
    const int tid = threadIdx.x;
    const int n    = cntg[t * CN1 + q];
    const int base = t * N_TOK + offg[t * CN1 + q];
    const int c0 = tid, c1 = tid + 256;
    const bool act1 = (c1 < C_DIM / 4);

    float a0x = 0.f, a0y = 0.f, a0z = 0.f, a0w = 0.f;
    float a1x = 0.f, a1y = 0.f, a1z = 0.f, a1w = 0.f;
    for (int m = 0; m < n; m++) {
        int row = memb[base + m];
        const float4* xr = (const float4*)(x + ((size_t)t * N_TOK + row) * C_DIM);
        float4 v0 = xr[c0];
        a0x += v0.x; a0y += v0.y; a0z += v0.z; a0w += v0.w;
        if (act1) {
            float4 v1 = xr[c1];
            a1x += v1.x; a1y += v1.y; a1z += v1.z; a1w += v1.w;
        }
    }
    float w = 1.0f / ((float)n + 1e-6f);
    float4* mr = (float4*)(meta1 + ((size_t)t * CN1 + q) * C_DIM);
    float4 o0; o0.x = a0x * w; o0.y = a0y * w; o0.z = a0z * w; o0.w = a0w * w;
    mr[c0] = o0;
    if (act1) {
        float4 o1; o1.x = a1x * w; o1.y = a1y * w; o1.z = a1z * w; o1.w = a1w * w;
        mr[c1] = o1;
    }
}

// ---------------------------------------------------------------------------
// Kernel DE: layer-2 DPC + merge2 + modulation + grouped output.
// One block (256 threads) per batch.
// ---------------------------------------------------------------------------
__global__ __launch_bounds__(256) void layer2_kernel(const float* __restrict__ meta1,
                                                     const float* __restrict__ score_w,
                                                     const float* __restrict__ score_b,
                                                     float* __restrict__ out) {
    const int t   = blockIdx.x;
    const int tid = threadIdx.x;
    const float* M = meta1 + (size_t)t * CN1 * C_DIM;

    __shared__ float buf[CN1][132];
    __shared__ float d2s[CN1][CN1];
    __shared__ float m2[CN2][C_DIM];
    __shared__ float dens[CN1], scor[CN1], nrm[CN1], rmx[CN1];
    __shared__ int   centers[CN2], idx2s[CN1], cnt2[CN2];
    __shared__ float modu[CN2], msum[CN2];
    __shared__ int   srcRow[NOUT], cidArr[NOUT];
    __shared__ float dmax_sh;

    const int ti = tid >> 4;
    const int tj = tid & 15;

    float acc = 0.f;
    for (int c0 = 0; c0 < C_DIM; c0 += 128) {
        for (int e = tid; e < CN1 * 128; e += 256) {
            int r = e >> 7, c = e & 127;
            buf[r][c] = M[(size_t)r * C_DIM + c0 + c];
        }
        __syncthreads();
#pragma unroll
        for (int cc = 0; cc < 128; cc += 4) {
            float4 a = *(const float4*)&buf[ti][cc];
            float4 b = *(const float4*)&buf[tj][cc];
            acc += a.x * b.x + a.y * b.y + a.z * b.z + a.w * b.w;
        }
        __syncthreads();
    }
    if (ti == tj) nrm[ti] = acc;
    __syncthreads();

    const float inv_sqrtC = 1.0f / sqrtf((float)C_DIM);
    {
        float d2 = nrm[ti] + nrm[tj] - 2.f * acc;
        d2s[ti][tj] = sqrtf(fmaxf(d2, 0.f)) * inv_sqrtC;
    }
    __syncthreads();

    if (tid < CN1) {
        float m0 = 3.4e38f, m1 = 3.4e38f, m2v = 3.4e38f, mx = 0.f;
        for (int j = 0; j < CN1; j++) {
            float d = d2s[tid][j];
            mx = fmaxf(mx, d);
            if (d < m2v) {
                m2v = d;
                if (m2v < m1) { float tmp = m2v; m2v = m1; m1 = tmp; }
                if (m1 < m0)  { float tmp = m1;  m1 = m0;  m0 = tmp; }
            }
        }
        dens[tid] = expf(-(m0 * m0 + m1 * m1 + m2v * m2v) / (float)KNN2);
        rmx[tid] = mx;
    }
    __syncthreads();
    if (tid == 0) {
        float g = 0.f;
        for (int j = 0; j < CN1; j++) g = fmaxf(g, rmx[j]);
        dmax_sh = g;
    }
    __syncthreads();

    if (tid < CN1) {
        float di = dens[tid];
        float pd = dmax_sh;
        for (int j = 0; j < CN1; j++)
            if (dens[j] > di) pd = fminf(pd, d2s[tid][j]);
        scor[tid] = pd * di;
    }
    __syncthreads();

    if (tid == 0) {
        for (int k = 0; k < CN2; k++) {
            float best = -3.4e38f; int bi = 0;
            for (int j = 0; j < CN1; j++)
                if (scor[j] > best) { best = scor[j]; bi = j; }
            centers[k] = bi;
            scor[bi] = -3.4e38f;
        }
    }
    __syncthreads();

    if (tid < CN1) {
        float bd = 3.4e38f; int bk = 0;
#pragma unroll
        for (int k = 0; k < CN2; k++) {
            float d = d2s[centers[k]][tid];
            if (d < bd) { bd = d; bk = k; }
        }
#pragma unroll
        for (int k = 0; k < CN2; k++) if (tid == centers[k]) bk = k;
        idx2s[tid] = bk;
    }
    __syncthreads();

    if (tid == 0) {
        for (int v = 0; v < CN2; v++) cnt2[v] = 0;
        for (int i = 0; i < CN1; i++) cnt2[idx2s[i]]++;
        int slot = 0;
        for (int v = 0; v < CN2; v++) {
            srcRow[slot] = CN1 + v; cidArr[slot] = v; slot++;
            for (int i = 0; i < CN1; i++)
                if (idx2s[i] == v) { srcRow[slot] = i; cidArr[slot] = v; slot++; }
        }
        for (int v = 0; v < CN2; v++) msum[v] = 0.f;
    }
    __syncthreads();

    float ls[CN2] = {0.f, 0.f, 0.f, 0.f, 0.f, 0.f};
    for (int ch = tid; ch < C_DIM; ch += 256) {
        float a6[CN2] = {0.f, 0.f, 0.f, 0.f, 0.f, 0.f};
        for (int r = 0; r < CN1; r++) {
            float v = M[(size_t)r * C_DIM + ch];
            int c = idx2s[r];
#pragma unroll
            for (int q = 0; q < CN2; q++) a6[q] += (c == q) ? v : 0.f;
        }
#pragma unroll
        for (int q = 0; q < CN2; q++) {
            float mv = a6[q] / ((float)cnt2[q] + 1e-6f);
            m2[q][ch] = mv;
            ls[q] += mv;
        }
    }
#pragma unroll
    for (int q = 0; q < CN2; q++) atomicAdd(&msum[q], ls[q]);
    __syncthreads();

    if (tid == 0) {
        float mean[CN2], lg[CN2];
        for (int v = 0; v < CN2; v++) mean[v] = msum[v] / (float)C_DIM;
        float mxl = -3.4e38f;
        for (int u = 0; u < CN2; u++) {
            float s = score_b[u];
            for (int v = 0; v < CN2; v++) s += mean[v] * score_w[u * CN2 + v];
            lg[u] = s;
            mxl = fmaxf(mxl, s);
        }
        float den = 0.f;
        for (int u = 0; u < CN2; u++) { lg[u] = expf(lg[u] - mxl); den += lg[u]; }
        for (int u = 0; u < CN2; u++) modu[u] = lg[u] / den;
    }
    __syncthreads();

    float* ob = out + (size_t)t * NOUT * C_DIM;
    for (int ch = tid; ch < C_DIM; ch += 256) {
#pragma unroll
        for (int s = 0; s < NOUT; s++) {
            int r = srcRow[s];
            float v = (r < CN1) ? M[(size_t)r * C_DIM + ch] : m2[r - CN1][ch];
            ob[(size_t)s * C_DIM + ch] = v * modu[cidArr[s]];
        }
    }
}

// ---------------------------------------------------------------------------
extern "C" void kernel_launch(void* const* d_in, const int* in_sizes, int n_in,
                              void* d_out, int out_size, void* d_ws, size_t ws_size,
                              hipStream_t stream) {
    const float* x  = (const float*)d_in[0];   // [128,256,1408]
    const float* sw = (const float*)d_in[1];   // [6,6]
    const float* sb = (const float*)d_in[2];   // [6]
    float* out = (float*)d_out;                // [128,22,1408]

    float* ws     = (float*)d_ws;
    float* dist   = ws;                                          // 8,388,608 f
    float* meta1  = dist + (size_t)T_BATCH * N_TOK * N_TOK;      // 2,883,584 f
    int*   memb   = (int*)(meta1 + (size_t)T_BATCH * CN1 * C_DIM); // 32768 i
    int*   cntg   = memb + (size_t)T_BATCH * N_TOK;              // 2048 i
    int*   offg   = cntg + T_BATCH * CN1;                        // 2048 i

    gemm_dist_sym<<<dim3(10, T_BATCH), 256, 0, stream>>>(x, dist);
    dpc1_fused<<<T_BATCH, 512, 0, stream>>>(dist, memb, cntg, offg);
    merge1_kernel<<<dim3(CN1, T_BATCH), 256, 0, stream>>>(x, memb, cntg, offg, meta1);
    layer2_kernel<<<T_BATCH, 256, 0, stream>>>(meta1, sw, sb, out);
}

// Round 7
// 429.809 us; speedup vs baseline: 2.1686x; 1.0327x over previous
//
#include <hip/hip_runtime.h>
#include <math.h>

#define T_BATCH 128
#define N_TOK   256
#define C_DIM   1408
#define CN1     16
#define KNN1    8
#define CN2     6
#define KNN2    3
#define NOUT    22   // CN2 + CN1
#define LS      44   // LDS row stride in shorts (22 words), 8B-aligned rows

typedef __attribute__((ext_vector_type(4))) short sh4;
typedef __attribute__((ext_vector_type(8))) short sh8;
typedef __attribute__((ext_vector_type(4))) float f32x4;

union frag_u { sh4 h[2]; sh8 v; };

__device__ inline sh8 ld_frag(const short* p) {
    frag_u u;
    u.h[0] = *(const sh4*)p;
    u.h[1] = *(const sh4*)(p + 4);
    return u.v;
}

// truncation split of a PAIR of fp32 -> packed bf16 hi pair + RNE bf16 lo pair.
__device__ inline void split2(float v0, float v1, unsigned& hip, unsigned& lop) {
    unsigned u0 = __float_as_uint(v0);
    unsigned u1 = __float_as_uint(v1);
    hip = (u0 >> 16) | (u1 & 0xFFFF0000u);
    float l0 = v0 - __uint_as_float(u0 & 0xFFFF0000u);
    float l1 = v1 - __uint_as_float(u1 & 0xFFFF0000u);
    unsigned w0 = __float_as_uint(l0);
    unsigned w1 = __float_as_uint(l1);
    w0 = w0 + 0x7FFFu + ((w0 >> 16) & 1u);
    w1 = w1 + 0x7FFFu + ((w1 >> 16) & 1u);
    lop = (w0 >> 16) | (w1 & 0xFFFF0000u);
}

// branchless insert of v into ascending 8-list m (keeps 8 smallest)
#define INS8(m, v) {                                   \
    float _x = (v);                                    \
    _Pragma("unroll")                                  \
    for (int _q = 0; _q < 8; _q++) {                   \
        float _lo = fminf(m[_q], _x);                  \
        _x = fmaxf(m[_q], _x);                         \
        m[_q] = _lo;                                   \
    }                                                  \
}

// ---------------------------------------------------------------------------
// Kernel A: dist via bf16x3 MFMA, 64x64 tiles, upper-tri pairs only.
// 1D grid with XCD swizzle: all 10 blocks of batch t share id%8 == t%8,
// so one batch's x rows live in one XCD's L2.
// ---------------------------------------------------------------------------
__global__ __launch_bounds__(256, 4) void gemm_dist_sym(const float* __restrict__ x,
                                                        float* __restrict__ dist) {
    const int id = blockIdx.x;
    const int r  = id & 7;
    const int q8 = id >> 3;          // 0..159
    const int p  = q8 % 10;
    const int tt = q8 / 10;          // 0..15
    const int t  = tt * 8 + r;
    const int bi = (p < 4) ? 0 : (p < 7) ? 1 : (p < 9) ? 2 : 3;
    const int bj = (p < 4) ? p : (p < 7) ? p - 3 : (p < 9) ? p - 5 : 3;
    const int i0 = bi * 64, j0 = bj * 64;
    const bool diag = (bi == bj);
    const float* X = x + (size_t)t * N_TOK * C_DIM;

    __shared__ short Ahi[64 * LS], Alo[64 * LS], Bhi[64 * LS], Blo[64 * LS];
    __shared__ float nred[512];
    __shared__ float snA[64], snB[64];

    const int tid  = threadIdx.x;
    const int wave = tid >> 6;
    const int lane = tid & 63;
    const int qr   = wave >> 1;
    const int qc   = wave & 1;
    const int srow = tid >> 2;
    const int sq   = tid & 3;
    const int fr   = lane & 15;
    const int fq   = lane >> 4;

    const short* BhiS = diag ? Ahi : Bhi;
    const short* BloS = diag ? Alo : Blo;

    f32x4 acc[2][2];
#pragma unroll
    for (int a = 0; a < 2; a++)
#pragma unroll
        for (int b = 0; b < 2; b++) acc[a][b] = (f32x4){0.f, 0.f, 0.f, 0.f};

    const float* Arow = X + (size_t)(i0 + srow) * C_DIM + sq * 8;
    const float* Brow = X + (size_t)(j0 + srow) * C_DIM + sq * 8;
    float nA = 0.f, nB = 0.f;

    for (int k0 = 0; k0 < C_DIM; k0 += 32) {
        float av[8], bv[8];
        float4 a0 = *(const float4*)(Arow + k0);
        float4 a1 = *(const float4*)(Arow + k0 + 4);
        av[0] = a0.x; av[1] = a0.y; av[2] = a0.z; av[3] = a0.w;
        av[4] = a1.x; av[5] = a1.y; av[6] = a1.z; av[7] = a1.w;
#pragma unroll
        for (int e = 0; e < 8; e++) nA += av[e] * av[e];
        unsigned ah[4], al[4], bh[4], bl[4];
#pragma unroll
        for (int q = 0; q < 4; q++) split2(av[2 * q], av[2 * q + 1], ah[q], al[q]);
        if (!diag) {
            float4 b0 = *(const float4*)(Brow + k0);
            float4 b1 = *(const float4*)(Brow + k0 + 4);
            bv[0] = b0.x; bv[1] = b0.y; bv[2] = b0.z; bv[3] = b0.w;
            bv[4] = b1.x; bv[5] = b1.y; bv[6] = b1.z; bv[7] = b1.w;
#pragma unroll
            for (int e = 0; e < 8; e++) nB += bv[e] * bv[e];
#pragma unroll
            for (int q = 0; q < 4; q++) split2(bv[2 * q], bv[2 * q + 1], bh[q], bl[q]);
        }
        __syncthreads();
        {
            unsigned* AH = (unsigned*)&Ahi[srow * LS + sq * 8];
            unsigned* AL = (unsigned*)&Alo[srow * LS + sq * 8];
#pragma unroll
            for (int q = 0; q < 4; q++) { AH[q] = ah[q]; AL[q] = al[q]; }
            if (!diag) {
                unsigned* BH = (unsigned*)&Bhi[srow * LS + sq * 8];
                unsigned* BL = (unsigned*)&Blo[srow * LS + sq * 8];
#pragma unroll
                for (int q = 0; q < 4; q++) { BH[q] = bh[q]; BL[q] = bl[q]; }
            }
        }
        __syncthreads();

        sh8 fAh[2], fAl[2], fBh[2], fBl[2];
#pragma unroll
        for (int mt = 0; mt < 2; mt++) {
            int ro = (qr * 32 + mt * 16 + fr) * LS + fq * 8;
            fAh[mt] = ld_frag(&Ahi[ro]);
            fAl[mt] = ld_frag(&Alo[ro]);
            int co = (qc * 32 + mt * 16 + fr) * LS + fq * 8;
            fBh[mt] = ld_frag(&BhiS[co]);
            fBl[mt] = ld_frag(&BloS[co]);
        }
#pragma unroll
        for (int mt = 0; mt < 2; mt++)
#pragma unroll
            for (int nt = 0; nt < 2; nt++) {
                acc[mt][nt] = __builtin_amdgcn_mfma_f32_16x16x32_bf16(fAh[mt], fBh[nt], acc[mt][nt], 0, 0, 0);
                acc[mt][nt] = __builtin_amdgcn_mfma_f32_16x16x32_bf16(fAh[mt], fBl[nt], acc[mt][nt], 0, 0, 0);
                acc[mt][nt] = __builtin_amdgcn_mfma_f32_16x16x32_bf16(fAl[mt], fBh[nt], acc[mt][nt], 0, 0, 0);
            }
    }

    nred[tid] = nA;
    nred[256 + tid] = diag ? nA : nB;
    __syncthreads();
    if (tid < 64) {
        snA[tid] = nred[4 * tid] + nred[4 * tid + 1] + nred[4 * tid + 2] + nred[4 * tid + 3];
        snB[tid] = nred[256 + 4 * tid] + nred[256 + 4 * tid + 1]
                 + nred[256 + 4 * tid + 2] + nred[256 + 4 * tid + 3];
    }
    __syncthreads();

    const float inv_sqrtC = 1.0f / sqrtf((float)C_DIM);
    float* Dt = dist + (size_t)t * N_TOK * N_TOK;
#pragma unroll
    for (int mt = 0; mt < 2; mt++)
#pragma unroll
        for (int nt = 0; nt < 2; nt++) {
            int jl = qc * 32 + nt * 16 + fr;
            int jg = j0 + jl;
            float sqj = snB[jl];
            int il0 = qr * 32 + mt * 16 + fq * 4;
            float vv[4];
#pragma unroll
            for (int rr = 0; rr < 4; rr++) {
                int ig = i0 + il0 + rr;
                float d2 = snA[il0 + rr] + sqj - 2.0f * acc[mt][nt][rr];
                float v = (ig == jg) ? 0.0f : sqrtf(fmaxf(d2, 0.0f)) * inv_sqrtC;
                Dt[(size_t)ig * N_TOK + jg] = v;
                vv[rr] = v;
            }
            if (!diag) {
                float4 o; o.x = vv[0]; o.y = vv[1]; o.z = vv[2]; o.w = vv[3];
                *(float4*)&Dt[(size_t)jg * N_TOK + i0 + il0] = o;
            }
        }
}

// ---------------------------------------------------------------------------
// Kernel B: fused layer-1 DPC. 1024 threads/block, one block per batch.
// 4 threads per column (64-row quarter scans), 2 chains each, LDS merge.
// ---------------------------------------------------------------------------
__global__ __launch_bounds__(1024) void dpc1_fused(const float* __restrict__ dist,
                                                   int* __restrict__ memb,
                                                   int* __restrict__ cntg,
                                                   int* __restrict__ offg) {
    const int t    = blockIdx.x;
    const int tid  = threadIdx.x;    // 0..1023
    const int col  = tid & 255;
    const int h    = tid >> 8;       // row quarter 0..3
    const int lane = tid & 63;
    const int wid  = tid >> 6;       // 0..15
    const float* D = dist + (size_t)t * N_TOK * N_TOK;

    __shared__ float dens_s[N_TOK];
    __shared__ float lists[KNN1][1024];
    __shared__ float red[1024];
    __shared__ float rmax16[16];
    __shared__ unsigned long long wred[16];
    __shared__ int centers[CN1];
    __shared__ int bks[N_TOK];
    __shared__ int cnt_s[CN1], off_s[CN1];

    // ---- pass 1: 8 smallest of this quarter-column, 2 chains ----
    float c0[8], c1[8];
#pragma unroll
    for (int q = 0; q < 8; q++) { c0[q] = 3.4e38f; c1[q] = 3.4e38f; }
    float mx = 0.f;
    const float* base = D + (size_t)(h * 64) * N_TOK + col;
    for (int jj = 0; jj < 64; jj += 2) {
        float d0 = base[(size_t)(jj + 0) * N_TOK];
        float d1 = base[(size_t)(jj + 1) * N_TOK];
        mx = fmaxf(mx, fmaxf(d0, d1));
        INS8(c0, d0); INS8(c1, d1);
    }
#pragma unroll
    for (int q = 0; q < 8; q++) { INS8(c0, c1[q]); }
#pragma unroll
    for (int q = 0; q < 8; q++) lists[q][tid] = c0[q];
    // dmax: wave shuffle-reduce, then 16-entry LDS
#pragma unroll
    for (int off = 32; off > 0; off >>= 1) mx = fmaxf(mx, __shfl_xor(mx, off));
    if (lane == 0) rmax16[wid] = mx;
    __syncthreads();
    float dmax = rmax16[0];
#pragma unroll
    for (int w = 1; w < 16; w++) dmax = fmaxf(dmax, rmax16[w]);

    if (h == 0) {
#pragma unroll
        for (int s = 1; s < 4; s++)
#pragma unroll
            for (int q = 0; q < 8; q++) { float v = lists[q][col + s * 256]; INS8(c0, v); }
        float s2 = 0.f;
#pragma unroll
        for (int q = 0; q < 8; q++) s2 += c0[q] * c0[q];
        dens_s[col] = expf(-s2 / (float)KNN1);
    }
    __syncthreads();
    const float dens = dens_s[col];

    // ---- pass 2: parent distance over this quarter, 2 chains ----
    float p0 = dmax, p1 = dmax;
    const float* dsh = dens_s + h * 64;
    for (int jj = 0; jj < 64; jj += 2) {
        float d0 = base[(size_t)(jj + 0) * N_TOK];
        float d1 = base[(size_t)(jj + 1) * N_TOK];
        p0 = (dsh[jj + 0] > dens) ? fminf(p0, d0) : p0;
        p1 = (dsh[jj + 1] > dens) ? fminf(p1, d1) : p1;
    }
    red[tid] = fminf(p0, p1);
    __syncthreads();
    float score = 0.f;
    if (h == 0)
        score = fminf(fminf(red[col], red[col + 256]),
                      fminf(red[col + 512], red[col + 768])) * dens;

    // ---- top-16 (desc, ties -> lowest index) ----
    unsigned long long key = 0;
    if (h == 0)
        key = ((unsigned long long)__float_as_uint(score) << 32) | (unsigned)(65535 - col);
    for (int k = 0; k < CN1; k++) {
        unsigned long long mm = key;
#pragma unroll
        for (int off = 32; off > 0; off >>= 1) {
            unsigned long long o = __shfl_xor(mm, off);
            mm = (o > mm) ? o : mm;
        }
        if (lane == 0) wred[wid] = mm;
        __syncthreads();
        unsigned long long b = wred[0];
#pragma unroll
        for (int w = 1; w < 16; w++) b = (wred[w] > b) ? wred[w] : b;
        int idx = 65535 - (int)(b & 0xFFFFull);
        if (tid == 0) centers[k] = idx;
        if (tid == idx) key = 0;
        __syncthreads();
    }

    // ---- assign + member lists (h==0 threads; barriers unconditional) ----
    int bk = 0;
    if (h == 0) {
        float bd = 3.4e38f;
#pragma unroll
        for (int k = 0; k < CN1; k++) {
            float d = D[(size_t)centers[k] * N_TOK + col];
            if (d < bd) { bd = d; bk = k; }
        }
#pragma unroll
        for (int k = 0; k < CN1; k++) if (col == centers[k]) bk = k;
        bks[col] = bk;
    }
    __syncthreads();
    if (tid < CN1) {
        int c = 0;
        for (int j = 0; j < N_TOK; j++) c += (bks[j] == tid);
        cnt_s[tid] = c;
    }
    __syncthreads();
    if (tid == 0) {
        int o = 0;
        for (int q = 0; q < CN1; q++) { off_s[q] = o; o += cnt_s[q]; }
    }
    __syncthreads();
    if (h == 0) {
        int rank = 0;
        for (int j = 0; j < col; j++) rank += (bks[j] == bk);
        memb[t * N_TOK + off_s[bk] + rank] = col;
    }
    if (tid < CN1) {
        cntg[t * CN1 + tid] = cnt_s[tid];
        offg[t * CN1 + tid] = off_s[tid];
    }
}

// ---------------------------------------------------------------------------
// Kernel C: merge1 via member lists, member loop unrolled x4 (4 independent
// row streams in flight; summation order preserved).
// ---------------------------------------------------------------------------
__global__ __launch_bounds__(256) void merge1_kernel(const float* __restrict__ x,
                                                     const int* __restrict__ memb,
                                                     const int* __restrict__ cntg,
                                                     const int* __restrict__ offg,
                                                     float* __restrict__ meta1) {
    const int q   = blockIdx.x;
    const int t   = blockIdx.y;
    const int tid = threadIdx.x;
    const int n    = cntg[t * CN1 + q];
    const int base = t * N_TOK + offg[t * CN1 + q];
    const int c0 = tid, c1 = tid + 256;
    const bool act1 = (c1 < C_DIM / 4);
    const float4* xb = (const float4*)(x + (size_t)t * N_TOK * C_DIM);
    const int stride4 = C_DIM / 4;

    float4 s0 = {0.f, 0.f, 0.f, 0.f};
    float4 s1 = {0.f, 0.f, 0.f, 0.f};
    int m = 0;
    for (; m + 4 <= n; m += 4) {
        int r0 = memb[base + m + 0];
        int r1 = memb[base + m + 1];
        int r2 = memb[base + m + 2];
        int r3 = memb[base + m + 3];
        float4 a0 = xb[(size_t)r0 * stride4 + c0];
        float4 a1 = xb[(size_t)r1 * stride4 + c0];
        float4 a2 = xb[(size_t)r2 * stride4 + c0];
        float4 a3 = xb[(size_t)r3 * stride4 + c0];
        s0.x += a0.x; s0.y += a0.y; s0.z += a0.z; s0.w += a0.w;
        s0.x += a1.x; s0.y += a1.y; s0.z += a1.z; s0.w += a1.w;
        s0.x += a2.x; s0.y += a2.y; s0.z += a2.z; s0.w += a2.w;
        s0.x += a3.x; s0.y += a3.y; s0.z += a3.z; s0.w += a3.w;
        if (act1) {
            float4 b0 = xb[(size_t)r0 * stride4 + c1];
            float4 b1 = xb[(size_t)r1 * stride4 + c1];
            float4 b2 = xb[(size_t)r2 * stride4 + c1];
            float4 b3 = xb[(size_t)r3 * stride4 + c1];
            s1.x += b0.x; s1.y += b0.y; s1.z += b0.z; s1.w += b0.w;
            s1.x += b1.x; s1.y += b1.y; s1.z += b1.z; s1.w += b1.w;
            s1.x += b2.x; s1.y += b2.y; s1.z += b2.z; s1.w += b2.w;
            s1.x += b3.x; s1.y += b3.y; s1.z += b3.z; s1.w += b3.w;
        }
    }
    for (; m < n; m++) {
        int r0 = memb[base + m];
        float4 a0 = xb[(size_t)r0 * stride4 + c0];
        s0.x += a0.x; s0.y += a0.y; s0.z += a0.z; s0.w += a0.w;
        if (act1) {
            float4 b0 = xb[(size_t)r0 * stride4 + c1];
            s1.x += b0.x; s1.y += b0.y; s1.z += b0.z; s1.w += b0.w;
        }
    }
    float w = 1.0f / ((float)n + 1e-6f);
    float4* mr = (float4*)(meta1 + ((size_t)t * CN1 + q) * C_DIM);
    float4 o0; o0.x = s0.x * w; o0.y = s0.y * w; o0.z = s0.z * w; o0.w = s0.w * w;
    mr[c0] = o0;
    if (act1) {
        float4 o1; o1.x = s1.x * w; o1.y = s1.y * w; o1.z = s1.z * w; o1.w = s1.w * w;
        mr[c1] = o1;
    }
}

// ---------------------------------------------------------------------------
// Kernel DE: layer-2 DPC + merge2 + modulation + grouped output.
// 1024 threads per block, one block per batch.
// ---------------------------------------------------------------------------
__global__ __launch_bounds__(1024) void layer2_kernel(const float* __restrict__ meta1,
                                                      const float* __restrict__ score_w,
                                                      const float* __restrict__ score_b,
                                                      float* __restrict__ out) {
    const int t   = blockIdx.x;
    const int tid = threadIdx.x;   // 0..1023
    const float* M = meta1 + (size_t)t * CN1 * C_DIM;

    __shared__ float buf[CN1][132];
    __shared__ float d2s[CN1][CN1];
    __shared__ float m2[CN2][C_DIM];
    __shared__ float dens[CN1], scor[CN1], nrm[CN1], rmx[CN1];
    __shared__ int   centers[CN2], idx2s[CN1], cnt2[CN2];
    __shared__ float modu[CN2], msum[CN2];
    __shared__ int   srcRow[NOUT], cidArr[NOUT];
    __shared__ float dmax_sh;

    const int ti = (tid < 256) ? (tid >> 4) : 0;
    const int tj = tid & 15;

    // ---- pairwise dots (threads 0-255 own one (i,j) pair; all stage) ----
    float acc = 0.f;
    for (int c0 = 0; c0 < C_DIM; c0 += 128) {
        for (int e = tid; e < CN1 * 128; e += 1024) {
            int r = e >> 7, c = e & 127;
            buf[r][c] = M[(size_t)r * C_DIM + c0 + c];
        }
        __syncthreads();
        if (tid < 256) {
#pragma unroll
            for (int cc = 0; cc < 128; cc += 4) {
                float4 a = *(const float4*)&buf[ti][cc];
                float4 b = *(const float4*)&buf[tj][cc];
                acc += a.x * b.x + a.y * b.y + a.z * b.z + a.w * b.w;
            }
        }
        __syncthreads();
    }
    if (tid < 256 && ti == tj) nrm[ti] = acc;
    __syncthreads();

    const float inv_sqrtC = 1.0f / sqrtf((float)C_DIM);
    if (tid < 256) {
        float d2 = nrm[ti] + nrm[tj] - 2.f * acc;
        d2s[ti][tj] = sqrtf(fmaxf(d2, 0.f)) * inv_sqrtC;
    }
    __syncthreads();

    if (tid < CN1) {
        float m0 = 3.4e38f, m1 = 3.4e38f, m2v = 3.4e38f, mx = 0.f;
        for (int j = 0; j < CN1; j++) {
            float d = d2s[tid][j];
            mx = fmaxf(mx, d);
            if (d < m2v) {
                m2v = d;
                if (m2v < m1) { float tmp = m2v; m2v = m1; m1 = tmp; }
                if (m1 < m0)  { float tmp = m1;  m1 = m0;  m0 = tmp; }
            }
        }
        dens[tid] = expf(-(m0 * m0 + m1 * m1 + m2v * m2v) / (float)KNN2);
        rmx[tid] = mx;
    }
    __syncthreads();
    if (tid == 0) {
        float g = 0.f;
        for (int j = 0; j < CN1; j++) g = fmaxf(g, rmx[j]);
        dmax_sh = g;
    }
    __syncthreads();

    if (tid < CN1) {
        float di = dens[tid];
        float pd = dmax_sh;
        for (int j = 0; j < CN1; j++)
            if (dens[j] > di) pd = fminf(pd, d2s[tid][j]);
        scor[tid] = pd * di;
    }
    __syncthreads();

    if (tid == 0) {
        for (int k = 0; k < CN2; k++) {
            float best = -3.4e38f; int bi = 0;
            for (int j = 0; j < CN1; j++)
                if (scor[j] > best) { best = scor[j]; bi = j; }
            centers[k] = bi;
            scor[bi] = -3.4e38f;
        }
    }
    __syncthreads();

    if (tid < CN1) {
        float bd = 3.4e38f; int bk = 0;
#pragma unroll
        for (int k = 0; k < CN2; k++) {
            float d = d2s[centers[k]][tid];
            if (d < bd) { bd = d; bk = k; }
        }
#pragma unroll
        for (int k = 0; k < CN2; k++) if (tid == centers[k]) bk = k;
        idx2s[tid] = bk;
    }
    __syncthreads();

    if (tid == 0) {
        for (int v = 0; v < CN2; v++) cnt2[v] = 0;
        for (int i = 0; i < CN1; i++) cnt2[idx2s[i]]++;
        int slot = 0;
        for (int v = 0; v < CN2; v++) {
            srcRow[slot] = CN1 + v; cidArr[slot] = v; slot++;
            for (int i = 0; i < CN1; i++)
                if (idx2s[i] == v) { srcRow[slot] = i; cidArr[slot] = v; slot++; }
        }
        for (int v = 0; v < CN2; v++) msum[v] = 0.f;
    }
    __syncthreads();

    // ---- meta2 scatter-mean + channel sums (1024-way over ch) ----
    float ls[CN2] = {0.f, 0.f, 0.f, 0.f, 0.f, 0.f};
    for (int ch = tid; ch < C_DIM; ch += 1024) {
        float a6[CN2] = {0.f, 0.f, 0.f, 0.f, 0.f, 0.f};
        for (int r = 0; r < CN1; r++) {
            float v = M[(size_t)r * C_DIM + ch];
            int c = idx2s[r];
#pragma unroll
            for (int q = 0; q < CN2; q++) a6[q] += (c == q) ? v : 0.f;
        }
#pragma unroll
        for (int q = 0; q < CN2; q++) {
            float mv = a6[q] / ((float)cnt2[q] + 1e-6f);
            m2[q][ch] = mv;
            ls[q] += mv;
        }
    }
#pragma unroll
    for (int q = 0; q < CN2; q++) atomicAdd(&msum[q], ls[q]);
    __syncthreads();

    if (tid == 0) {
        float mean[CN2], lg[CN2];
        for (int v = 0; v < CN2; v++) mean[v] = msum[v] / (float)C_DIM;
        float mxl = -3.4e38f;
        for (int u = 0; u < CN2; u++) {
            float s = score_b[u];
            for (int v = 0; v < CN2; v++) s += mean[v] * score_w[u * CN2 + v];
            lg[u] = s;
            mxl = fmaxf(mxl, s);
        }
        float den = 0.f;
        for (int u = 0; u < CN2; u++) { lg[u] = expf(lg[u] - mxl); den += lg[u]; }
        for (int u = 0; u < CN2; u++) modu[u] = lg[u] / den;
    }
    __syncthreads();

    // ---- grouped, scaled output (1024-way over ch) ----
    float* ob = out + (size_t)t * NOUT * C_DIM;
    for (int ch = tid; ch < C_DIM; ch += 1024) {
#pragma unroll
        for (int s = 0; s < NOUT; s++) {
            int r = srcRow[s];
            float v = (r < CN1) ? M[(size_t)r * C_DIM + ch] : m2[r - CN1][ch];
            ob[(size_t)s * C_DIM + ch] = v * modu[cidArr[s]];
        }
    }
}

// ---------------------------------------------------------------------------
extern "C" void kernel_launch(void* const* d_in, const int* in_sizes, int n_in,
                              void* d_out, int out_size, void* d_ws, size_t ws_size,
                              hipStream_t stream) {
    const float* x  = (const float*)d_in[0];   // [128,256,1408]
    const float* sw = (const float*)d_in[1];   // [6,6]
    const float* sb = (const float*)d_in[2];   // [6]
    float* out = (float*)d_out;                // [128,22,1408]

    float* ws     = (float*)d_ws;
    float* dist   = ws;                                          // 8,388,608 f
    float* meta1  = dist + (size_t)T_BATCH * N_TOK * N_TOK;      // 2,883,584 f
    int*   memb   = (int*)(meta1 + (size_t)T_BATCH * CN1 * C_DIM); // 32768 i
    int*   cntg   = memb + (size_t)T_BATCH * N_TOK;              // 2048 i
    int*   offg   = cntg + T_BATCH * CN1;                        // 2048 i

    gemm_dist_sym<<<1280, 256, 0, stream>>>(x, dist);
    dpc1_fused<<<T_BATCH, 1024, 0, stream>>>(dist, memb, cntg, offg);
    merge1_kernel<<<dim3(CN1, T_BATCH), 256, 0, stream>>>(x, memb, cntg, offg, meta1);
    layer2_kernel<<<T_BATCH, 1024, 0, stream>>>(meta1, sw, sb, out);
}